// Round 1
// baseline (1205.405 us; speedup 1.0000x reference)
//
#include <hip/hip_runtime.h>
#include <math.h>

#define NN 20000
#define EE 256000
#define GG 64
#define CDIV(a,b) (((a)+(b)-1)/(b))

// ---------------- graph preprocessing ----------------

__global__ void k_prep(int* deg) {
  int i = blockIdx.x*blockDim.x + threadIdx.x;
  if (i < NN) deg[i] = 1;   // self-loop
}

__global__ void k_deg(const int* __restrict__ dst, int* deg) {
  int i = blockIdx.x*blockDim.x + threadIdx.x;
  if (i < EE) atomicAdd(&deg[dst[i]], 1);
}

// single-block exclusive scan of deg -> offsets; also dinv, cursor
__global__ void k_scan(const int* __restrict__ deg, int* __restrict__ offsets,
                       int* __restrict__ cursor, float* __restrict__ dinv) {
  __shared__ int sums[1024];
  const int PER = 20;  // 1024*20 = 20480 >= 20000
  int t = threadIdx.x;
  int base = t * PER;
  int local[PER];
  int s = 0;
  #pragma unroll
  for (int i = 0; i < PER; ++i) {
    int idx = base + i;
    int d = (idx < NN) ? deg[idx] : 0;
    local[i] = s;
    s += d;
  }
  sums[t] = s;
  __syncthreads();
  for (int off = 1; off < 1024; off <<= 1) {
    int v = (t >= off) ? sums[t - off] : 0;
    __syncthreads();
    sums[t] += v;
    __syncthreads();
  }
  int block_excl = (t == 0) ? 0 : sums[t - 1];
  #pragma unroll
  for (int i = 0; i < PER; ++i) {
    int idx = base + i;
    if (idx < NN) {
      int off = block_excl + local[i];
      offsets[idx] = off;
      cursor[idx]  = off;
      dinv[idx] = rsqrtf((float)deg[idx]);
    }
  }
  if (t == 1023) offsets[NN] = sums[1023];
}

__global__ void k_fill(const int* __restrict__ srcv, const int* __restrict__ dstv,
                       const float* __restrict__ dinv, int* cursor,
                       int* __restrict__ csr_src, float* __restrict__ csr_w) {
  int i = blockIdx.x*blockDim.x + threadIdx.x;
  if (i < EE) {
    int s = srcv[i], d = dstv[i];
    int pos = atomicAdd(&cursor[d], 1);
    csr_src[pos] = s;
    csr_w[pos] = dinv[s] * dinv[d];
  } else if (i < EE + NN) {
    int n = i - EE;
    int pos = atomicAdd(&cursor[n], 1);
    csr_src[pos] = n;
    float di = dinv[n];
    csr_w[pos] = di * di;
  }
}

__global__ void k_goff(const int* __restrict__ batch, int* __restrict__ goff) {
  int i = blockIdx.x*blockDim.x + threadIdx.x;
  if (i >= NN) return;
  int b = batch[i];
  int bp = (i == 0) ? -1 : batch[i-1];
  for (int g = bp + 1; g <= b; ++g) goff[g] = i;
  if (i == NN-1) for (int g = b+1; g <= GG; ++g) goff[g] = NN;
}

// ---------------- aggregation: out[n,:] = sum_{e in CSR(n)} w_e * in[src_e,:] ----------------

template<int C, int TX, int TY>
__global__ void k_agg(const float* __restrict__ in, const int* __restrict__ offsets,
                      const int* __restrict__ csr_src, const float* __restrict__ csr_w,
                      float* __restrict__ out) {
  int node = blockIdx.x * TY + threadIdx.y;
  if (node >= NN) return;
  int x = threadIdx.x;
  int k0 = offsets[node], k1 = offsets[node+1];
  if (x < C) {
    float acc = 0.f;
    for (int k = k0; k < k1; ++k) {
      int s = csr_src[k];
      float w = csr_w[k];
      acc += w * in[s*C + x];
    }
    out[node*C + x] = acc;
  }
}

// ---------------- small GEMM (layers 1-3): out = A[N,K] @ W[K,OUT] + b ----------------

template<int K, int OUT, int ROWS>
__global__ __launch_bounds__(256) void k_gemm_small(
    const float* __restrict__ A, const float* __restrict__ W,
    const float* __restrict__ b, float* __restrict__ out) {
  __shared__ float Ws[K*OUT];
  __shared__ float As[ROWS*K];
  int t = threadIdx.x;
  for (int i = t; i < K*OUT; i += 256) Ws[i] = W[i];
  int row0 = blockIdx.x * ROWS;   // N divisible by ROWS (20000 % 16/32 == 0)
  for (int i = t; i < ROWS*K; i += 256) As[i] = A[row0*K + i];
  __syncthreads();
  const int RG  = 256 / OUT;    // row groups
  const int RPT = ROWS / RG;    // rows per thread
  int j  = t % OUT;
  int rg = t / OUT;
  float bias = b[j];
  float acc[RPT];
  #pragma unroll
  for (int i = 0; i < RPT; ++i) acc[i] = bias;
  for (int k = 0; k < K; ++k) {
    float w = Ws[k*OUT + j];
    #pragma unroll
    for (int i = 0; i < RPT; ++i)
      acc[i] += As[(rg*RPT + i)*K + k] * w;
  }
  #pragma unroll
  for (int i = 0; i < RPT; ++i)
    out[(row0 + rg*RPT + i)*OUT + j] = acc[i];
}

// ---------------- layer-4 GEMM: [20000,128] @ [128,1024] + b, fp32 tiled ----------------

__global__ __launch_bounds__(256) void k_gemm_l4(
    const float* __restrict__ A, const float* __restrict__ W,
    const float* __restrict__ bias, float* __restrict__ out) {
  __shared__ float As[64][65];
  __shared__ float Bs[64][64];
  int row0 = blockIdx.x * 64;
  int col0 = blockIdx.y * 64;
  int t = threadIdx.x;
  int tx = t % 16, ty = t / 16;
  float acc[4][4] = {};
  for (int kc = 0; kc < 128; kc += 64) {
    int lr = t / 16;
    int lc = (t % 16) * 4;
    #pragma unroll
    for (int rr = 0; rr < 64; rr += 16) {
      int r = row0 + rr + lr;
      float4 v = make_float4(0.f,0.f,0.f,0.f);
      if (r < NN) v = *(const float4*)&A[r*128 + kc + lc];
      As[rr+lr][lc+0]=v.x; As[rr+lr][lc+1]=v.y; As[rr+lr][lc+2]=v.z; As[rr+lr][lc+3]=v.w;
    }
    #pragma unroll
    for (int rr = 0; rr < 64; rr += 16) {
      float4 v = *(const float4*)&W[(kc+rr+lr)*1024 + col0 + lc];
      *(float4*)&Bs[rr+lr][lc] = v;
    }
    __syncthreads();
    #pragma unroll
    for (int kk = 0; kk < 64; ++kk) {
      float a[4], bv[4];
      #pragma unroll
      for (int i=0;i<4;++i) a[i] = As[ty*4+i][kk];
      #pragma unroll
      for (int j=0;j<4;++j) bv[j] = Bs[kk][tx*4+j];
      #pragma unroll
      for (int i=0;i<4;++i)
        #pragma unroll
        for (int j=0;j<4;++j)
          acc[i][j] += a[i]*bv[j];
    }
    __syncthreads();
  }
  float4 bv = *(const float4*)&bias[col0 + tx*4];
  #pragma unroll
  for (int i=0;i<4;++i) {
    int r = row0 + ty*4 + i;
    if (r < NN) {
      float4 o = make_float4(acc[i][0]+bv.x, acc[i][1]+bv.y, acc[i][2]+bv.z, acc[i][3]+bv.w);
      *(float4*)&out[r*1024 + col0 + tx*4] = o;
    }
  }
}

// ---------------- batchnorm pieces ----------------

__global__ void k_stats(const float* __restrict__ h, float* __restrict__ stats,
                        int C, int rows_per_block) {
  int c = blockIdx.x*64 + threadIdx.x;
  int r0 = blockIdx.y * rows_per_block;
  int r1 = min(NN, r0 + rows_per_block);
  float s = 0.f, ss = 0.f;
  if (c < C) {
    for (int r = r0 + threadIdx.y; r < r1; r += 4) {
      float v = h[r*C + c];
      s += v; ss += v*v;
    }
  }
  __shared__ float red[2][4][64];
  red[0][threadIdx.y][threadIdx.x] = s;
  red[1][threadIdx.y][threadIdx.x] = ss;
  __syncthreads();
  if (threadIdx.y == 0 && c < C) {
    s  = red[0][0][threadIdx.x]+red[0][1][threadIdx.x]+red[0][2][threadIdx.x]+red[0][3][threadIdx.x];
    ss = red[1][0][threadIdx.x]+red[1][1][threadIdx.x]+red[1][2][threadIdx.x]+red[1][3][threadIdx.x];
    atomicAdd(&stats[c], s);
    atomicAdd(&stats[C+c], ss);
  }
}

__global__ void k_finalize(float* stats, int C, float invN) {
  int c = blockIdx.x*blockDim.x + threadIdx.x;
  if (c < C) {
    float m = stats[c] * invN;
    float v = stats[C+c]*invN - m*m;
    stats[c] = m;
    stats[C+c] = rsqrtf(v + 1e-5f);
  }
}

__global__ void k_bnrelu(const float* __restrict__ h, const float* __restrict__ stats,
                         const float* __restrict__ g, const float* __restrict__ be,
                         float* __restrict__ out, int total, int C) {
  int i = blockIdx.x*blockDim.x + threadIdx.x;
  if (i >= total) return;
  int c = i % C;
  float m = stats[c], rstd = stats[C+c];
  float v = (h[i]-m)*rstd*g[c] + be[c];
  out[i] = fmaxf(v, 0.f);
}

// pool with BN+ReLU fused: p[g,c] = max_n relu(bn(h4[n,c]))
__global__ void k_pool(const float* __restrict__ h4, const float* __restrict__ stats,
                       const float* __restrict__ g, const float* __restrict__ be,
                       const int* __restrict__ goff, float* __restrict__ p) {
  int gph = blockIdx.x;
  int col = blockIdx.y*64 + threadIdx.x;
  int r0 = goff[gph], r1 = goff[gph+1];
  float m = stats[col], rstd = stats[1024+col];
  float scale = g[col]*rstd;
  float shift = be[col] - m*scale;
  float mx = 0.f;   // relu floor
  for (int r = r0; r < r1; ++r) {
    float v = h4[r*1024 + col]*scale + shift;
    mx = fmaxf(mx, v);
  }
  p[gph*1024 + col] = mx;
}

// ---------------- FC head ----------------

template<int K, int OUT>
__global__ void k_fc(const float* __restrict__ A, const float* __restrict__ W,
                     const float* __restrict__ b, float* __restrict__ out) {
  // A [64,K], W [K,OUT]; grid OUT/64, block (64,4)
  int j  = blockIdx.x*64 + threadIdx.x;
  int ty = threadIdx.y;
  float acc[16];
  float bias = b[j];
  #pragma unroll
  for (int i=0;i<16;++i) acc[i] = bias;
  for (int k = 0; k < K; ++k) {
    float w = W[k*OUT + j];
    #pragma unroll
    for (int i=0;i<16;++i) acc[i] += A[(ty*16+i)*K + k] * w;
  }
  #pragma unroll
  for (int i=0;i<16;++i) out[(ty*16+i)*OUT + j] = acc[i];
}

__global__ void k_bn_rows(float* __restrict__ h, const float* __restrict__ g,
                          const float* __restrict__ be, int C) {
  int c = blockIdx.x*64 + threadIdx.x;
  if (c >= C) return;
  float s=0.f, ss=0.f;
  for (int r=0;r<64;++r){ float v=h[r*C+c]; s+=v; ss+=v*v; }
  float m = s*(1.f/64.f);
  float var = ss*(1.f/64.f)-m*m;
  float rstd = rsqrtf(var+1e-5f);
  float sc = g[c]*rstd, sh = be[c]-m*sc;
  for (int r=0;r<64;++r){ float v=h[r*C+c]*sc+sh; h[r*C+c]=fmaxf(v,0.f); }
}

__global__ void k_fc3(const float* __restrict__ A, const float* __restrict__ W,
                      const float* __restrict__ b, float* __restrict__ out) {
  int r = blockIdx.x, j = threadIdx.x;
  float acc = b[j];
  for (int k=0;k<256;++k) acc += A[r*256+k]*W[k*64+j];
  float ss = acc*acc;
  #pragma unroll
  for (int off=1; off<64; off<<=1) ss += __shfl_xor(ss, off);
  float norm = sqrtf(ss);
  float inv = 1.f / fmaxf(norm, 1e-12f);
  out[r*64+j] = acc * inv;
}

// ---------------- launch ----------------

extern "C" void kernel_launch(void* const* d_in, const int* in_sizes, int n_in,
                              void* d_out, int out_size, void* d_ws, size_t ws_size,
                              hipStream_t stream) {
  const float* x    = (const float*)d_in[0];
  const int*   ei   = (const int*)d_in[1];
  const int*   batch= (const int*)d_in[2];
  const float* W1=(const float*)d_in[3],  *b1=(const float*)d_in[4],  *g1=(const float*)d_in[5],  *be1=(const float*)d_in[6];
  const float* W2=(const float*)d_in[7],  *b2=(const float*)d_in[8],  *g2=(const float*)d_in[9],  *be2=(const float*)d_in[10];
  const float* W3=(const float*)d_in[11], *b3=(const float*)d_in[12], *g3=(const float*)d_in[13], *be3=(const float*)d_in[14];
  const float* W4=(const float*)d_in[15], *b4=(const float*)d_in[16], *g4=(const float*)d_in[17], *be4=(const float*)d_in[18];
  const float* W5=(const float*)d_in[19], *b5=(const float*)d_in[20], *g5=(const float*)d_in[21], *be5=(const float*)d_in[22];
  const float* W6=(const float*)d_in[23], *b6=(const float*)d_in[24], *g6=(const float*)d_in[25], *be6=(const float*)d_in[26];
  const float* W7=(const float*)d_in[27], *b7=(const float*)d_in[28];
  const int* esrc = ei;
  const int* edst = ei + EE;

  // workspace layout
  char* w = (char*)d_ws;
  auto alloc = [&](size_t bytes) -> void* {
    void* p = (void*)w;
    w += (bytes + 255) & ~(size_t)255;
    return p;
  };
  int*   deg     = (int*)  alloc(NN*4);
  int*   offsets = (int*)  alloc((NN+1)*4);
  int*   cursor  = (int*)  alloc(NN*4);
  int*   goff    = (int*)  alloc((GG+1)*4);
  float* dinv    = (float*)alloc(NN*4);
  int*   csr_src = (int*)  alloc((EE+NN)*4);
  float* csr_w   = (float*)alloc((EE+NN)*4);
  float* stats   = (float*)alloc(2*1024*4);
  float* agg     = (float*)alloc((size_t)NN*128*4);
  float* hbuf    = (float*)alloc((size_t)NN*128*4);
  float* hnorm   = (float*)alloc((size_t)NN*128*4);
  float* pooled  = (float*)alloc(64*1024*4);
  float* fc1     = (float*)alloc(64*512*4);
  float* fc2     = (float*)alloc(64*256*4);
  float* h4      = (float*)alloc((size_t)NN*1024*4);

  const int RPB = CDIV(NN, 64);  // stats rows per block-y

  // graph prep
  k_prep<<<CDIV(NN,256),256,0,stream>>>(deg);
  k_deg<<<CDIV(EE,256),256,0,stream>>>(edst, deg);
  k_scan<<<1,1024,0,stream>>>(deg, offsets, cursor, dinv);
  k_fill<<<CDIV(EE+NN,256),256,0,stream>>>(esrc, edst, dinv, cursor, csr_src, csr_w);
  k_goff<<<CDIV(NN,256),256,0,stream>>>(batch, goff);

  // ---- layer 1: agg(x)@W1 + b1, BN, relu ----
  k_agg<6,8,32><<<CDIV(NN,32),dim3(8,32),0,stream>>>(x, offsets, csr_src, csr_w, agg);
  k_gemm_small<6,32,32><<<NN/32,256,0,stream>>>(agg, W1, b1, hbuf);
  hipMemsetAsync(stats, 0, 2*32*4, stream);
  k_stats<<<dim3(1,64),dim3(64,4),0,stream>>>(hbuf, stats, 32, RPB);
  k_finalize<<<1,64,0,stream>>>(stats, 32, 1.f/NN);
  k_bnrelu<<<CDIV(NN*32,256),256,0,stream>>>(hbuf, stats, g1, be1, hnorm, NN*32, 32);

  // ---- layer 2 ----
  k_agg<32,32,8><<<CDIV(NN,8),dim3(32,8),0,stream>>>(hnorm, offsets, csr_src, csr_w, agg);
  k_gemm_small<32,64,16><<<NN/16,256,0,stream>>>(agg, W2, b2, hbuf);
  hipMemsetAsync(stats, 0, 2*64*4, stream);
  k_stats<<<dim3(1,64),dim3(64,4),0,stream>>>(hbuf, stats, 64, RPB);
  k_finalize<<<1,64,0,stream>>>(stats, 64, 1.f/NN);
  k_bnrelu<<<CDIV(NN*64,256),256,0,stream>>>(hbuf, stats, g2, be2, hnorm, NN*64, 64);

  // ---- layer 3 ----
  k_agg<64,64,4><<<CDIV(NN,4),dim3(64,4),0,stream>>>(hnorm, offsets, csr_src, csr_w, agg);
  k_gemm_small<64,128,16><<<NN/16,256,0,stream>>>(agg, W3, b3, hbuf);
  hipMemsetAsync(stats, 0, 2*128*4, stream);
  k_stats<<<dim3(2,64),dim3(64,4),0,stream>>>(hbuf, stats, 128, RPB);
  k_finalize<<<1,128,0,stream>>>(stats, 128, 1.f/NN);
  k_bnrelu<<<CDIV(NN*128,256),256,0,stream>>>(hbuf, stats, g3, be3, hnorm, NN*128, 128);

  // ---- layer 4 ----
  k_agg<128,128,2><<<CDIV(NN,2),dim3(128,2),0,stream>>>(hnorm, offsets, csr_src, csr_w, agg);
  k_gemm_l4<<<dim3(CDIV(NN,64),16),256,0,stream>>>(agg, W4, b4, h4);
  hipMemsetAsync(stats, 0, 2*1024*4, stream);
  k_stats<<<dim3(16,64),dim3(64,4),0,stream>>>(h4, stats, 1024, RPB);
  k_finalize<<<4,256,0,stream>>>(stats, 1024, 1.f/NN);
  // pool (BN+relu fused)
  k_pool<<<dim3(GG,16),64,0,stream>>>(h4, stats, g4, be4, goff, pooled);

  // ---- FC head ----
  k_fc<1024,512><<<8,dim3(64,4),0,stream>>>(pooled, W5, b5, fc1);
  k_bn_rows<<<8,64,0,stream>>>(fc1, g5, be5, 512);
  k_fc<512,256><<<4,dim3(64,4),0,stream>>>(fc1, W6, b6, fc2);
  k_bn_rows<<<4,64,0,stream>>>(fc2, g6, be6, 256);
  k_fc3<<<64,64,0,stream>>>(fc2, W7, b7, (float*)d_out);
}

// Round 2
// 697.591 us; speedup vs baseline: 1.7280x; 1.7280x over previous
//
#include <hip/hip_runtime.h>
#include <math.h>

#define NN 20000
#define EE 256000
#define GG 64
#define CDIV(a,b) (((a)+(b)-1)/(b))

// ---------------- graph preprocessing ----------------

__global__ void k_prep(int* deg) {
  int i = blockIdx.x*blockDim.x + threadIdx.x;
  if (i < NN) deg[i] = 1;   // self-loop
}

__global__ void k_deg(const int* __restrict__ dst, int* deg) {
  int i = blockIdx.x*blockDim.x + threadIdx.x;
  if (i < EE) atomicAdd(&deg[dst[i]], 1);
}

// single-block exclusive scan of deg -> offsets; also dinv, cursor
__global__ void k_scan(const int* __restrict__ deg, int* __restrict__ offsets,
                       int* __restrict__ cursor, float* __restrict__ dinv) {
  __shared__ int sums[1024];
  const int PER = 20;  // 1024*20 = 20480 >= 20000
  int t = threadIdx.x;
  int base = t * PER;
  int local[PER];
  int s = 0;
  #pragma unroll
  for (int i = 0; i < PER; ++i) {
    int idx = base + i;
    int d = (idx < NN) ? deg[idx] : 0;
    local[i] = s;
    s += d;
  }
  sums[t] = s;
  __syncthreads();
  for (int off = 1; off < 1024; off <<= 1) {
    int v = (t >= off) ? sums[t - off] : 0;
    __syncthreads();
    sums[t] += v;
    __syncthreads();
  }
  int block_excl = (t == 0) ? 0 : sums[t - 1];
  #pragma unroll
  for (int i = 0; i < PER; ++i) {
    int idx = base + i;
    if (idx < NN) {
      int off = block_excl + local[i];
      offsets[idx] = off;
      cursor[idx]  = off;
      dinv[idx] = rsqrtf((float)deg[idx]);
    }
  }
  if (t == 1023) offsets[NN] = sums[1023];
}

__global__ void k_fill(const int* __restrict__ srcv, const int* __restrict__ dstv,
                       const float* __restrict__ dinv, int* cursor,
                       int* __restrict__ csr_src, float* __restrict__ csr_w) {
  int i = blockIdx.x*blockDim.x + threadIdx.x;
  if (i < EE) {
    int s = srcv[i], d = dstv[i];
    int pos = atomicAdd(&cursor[d], 1);
    csr_src[pos] = s;
    csr_w[pos] = dinv[s] * dinv[d];
  } else if (i < EE + NN) {
    int n = i - EE;
    int pos = atomicAdd(&cursor[n], 1);
    csr_src[pos] = n;
    float di = dinv[n];
    csr_w[pos] = di * di;
  }
}

__global__ void k_goff(const int* __restrict__ batch, int* __restrict__ goff) {
  int i = blockIdx.x*blockDim.x + threadIdx.x;
  if (i >= NN) return;
  int b = batch[i];
  int bp = (i == 0) ? -1 : batch[i-1];
  for (int g = bp + 1; g <= b; ++g) goff[g] = i;
  if (i == NN-1) for (int g = b+1; g <= GG; ++g) goff[g] = NN;
}

// ---------------- aggregation: out[n,:] = sum_{e in CSR(n)} w_e * in[src_e,:] ----------------

template<int C, int TX, int TY>
__global__ void k_agg(const float* __restrict__ in, const int* __restrict__ offsets,
                      const int* __restrict__ csr_src, const float* __restrict__ csr_w,
                      float* __restrict__ out) {
  int node = blockIdx.x * TY + threadIdx.y;
  if (node >= NN) return;
  int x = threadIdx.x;
  int k0 = offsets[node], k1 = offsets[node+1];
  if (x < C) {
    float acc = 0.f;
    for (int k = k0; k < k1; ++k) {
      int s = csr_src[k];
      float w = csr_w[k];
      acc += w * in[s*C + x];
    }
    out[node*C + x] = acc;
  }
}

// ---------------- small GEMM (layers 1-3): out = A[N,K] @ W[K,OUT] + b ----------------

template<int K, int OUT, int ROWS>
__global__ __launch_bounds__(256) void k_gemm_small(
    const float* __restrict__ A, const float* __restrict__ W,
    const float* __restrict__ b, float* __restrict__ out) {
  __shared__ float Ws[K*OUT];
  __shared__ float As[ROWS*K];
  int t = threadIdx.x;
  for (int i = t; i < K*OUT; i += 256) Ws[i] = W[i];
  int row0 = blockIdx.x * ROWS;   // N divisible by ROWS
  for (int i = t; i < ROWS*K; i += 256) As[i] = A[row0*K + i];
  __syncthreads();
  const int RG  = 256 / OUT;    // row groups
  const int RPT = ROWS / RG;    // rows per thread
  int j  = t % OUT;
  int rg = t / OUT;
  float bias = b[j];
  float acc[RPT];
  #pragma unroll
  for (int i = 0; i < RPT; ++i) acc[i] = bias;
  for (int k = 0; k < K; ++k) {
    float w = Ws[k*OUT + j];
    #pragma unroll
    for (int i = 0; i < RPT; ++i)
      acc[i] += As[(rg*RPT + i)*K + k] * w;
  }
  #pragma unroll
  for (int i = 0; i < RPT; ++i)
    out[(row0 + rg*RPT + i)*OUT + j] = acc[i];
}

// ---------------- layer-4 GEMM: [20000,128] @ [128,1024] + b, fp32 tiled ----------------

__global__ __launch_bounds__(256) void k_gemm_l4(
    const float* __restrict__ A, const float* __restrict__ W,
    const float* __restrict__ bias, float* __restrict__ out) {
  __shared__ float As[64][65];
  __shared__ float Bs[64][64];
  int row0 = blockIdx.x * 64;
  int col0 = blockIdx.y * 64;
  int t = threadIdx.x;
  int tx = t % 16, ty = t / 16;
  float acc[4][4] = {};
  for (int kc = 0; kc < 128; kc += 64) {
    int lr = t / 16;
    int lc = (t % 16) * 4;
    #pragma unroll
    for (int rr = 0; rr < 64; rr += 16) {
      int r = row0 + rr + lr;
      float4 v = make_float4(0.f,0.f,0.f,0.f);
      if (r < NN) v = *(const float4*)&A[r*128 + kc + lc];
      As[rr+lr][lc+0]=v.x; As[rr+lr][lc+1]=v.y; As[rr+lr][lc+2]=v.z; As[rr+lr][lc+3]=v.w;
    }
    #pragma unroll
    for (int rr = 0; rr < 64; rr += 16) {
      float4 v = *(const float4*)&W[(kc+rr+lr)*1024 + col0 + lc];
      *(float4*)&Bs[rr+lr][lc] = v;
    }
    __syncthreads();
    #pragma unroll
    for (int kk = 0; kk < 64; ++kk) {
      float a[4], bv[4];
      #pragma unroll
      for (int i=0;i<4;++i) a[i] = As[ty*4+i][kk];
      #pragma unroll
      for (int j=0;j<4;++j) bv[j] = Bs[kk][tx*4+j];
      #pragma unroll
      for (int i=0;i<4;++i)
        #pragma unroll
        for (int j=0;j<4;++j)
          acc[i][j] += a[i]*bv[j];
    }
    __syncthreads();
  }
  float4 bv = *(const float4*)&bias[col0 + tx*4];
  #pragma unroll
  for (int i=0;i<4;++i) {
    int r = row0 + ty*4 + i;
    if (r < NN) {
      float4 o = make_float4(acc[i][0]+bv.x, acc[i][1]+bv.y, acc[i][2]+bv.z, acc[i][3]+bv.w);
      *(float4*)&out[r*1024 + col0 + tx*4] = o;
    }
  }
}

// ---------------- batchnorm pieces ----------------

__global__ void k_stats(const float* __restrict__ h, float* __restrict__ stats,
                        int C, int rows_per_block) {
  int c = blockIdx.x*64 + threadIdx.x;
  int r0 = blockIdx.y * rows_per_block;
  int r1 = min(NN, r0 + rows_per_block);
  float s = 0.f, ss = 0.f;
  if (c < C) {
    for (int r = r0 + threadIdx.y; r < r1; r += 4) {
      float v = h[r*C + c];
      s += v; ss += v*v;
    }
  }
  __shared__ float red[2][4][64];
  red[0][threadIdx.y][threadIdx.x] = s;
  red[1][threadIdx.y][threadIdx.x] = ss;
  __syncthreads();
  if (threadIdx.y == 0 && c < C) {
    s  = red[0][0][threadIdx.x]+red[0][1][threadIdx.x]+red[0][2][threadIdx.x]+red[0][3][threadIdx.x];
    ss = red[1][0][threadIdx.x]+red[1][1][threadIdx.x]+red[1][2][threadIdx.x]+red[1][3][threadIdx.x];
    atomicAdd(&stats[c], s);
    atomicAdd(&stats[C+c], ss);
  }
}

__global__ void k_finalize(float* stats, int C, float invN) {
  int c = blockIdx.x*blockDim.x + threadIdx.x;
  if (c < C) {
    float m = stats[c] * invN;
    float v = stats[C+c]*invN - m*m;
    stats[c] = m;
    stats[C+c] = rsqrtf(v + 1e-5f);
  }
}

__global__ void k_bnrelu(const float* __restrict__ h, const float* __restrict__ stats,
                         const float* __restrict__ g, const float* __restrict__ be,
                         float* __restrict__ out, int total, int C) {
  int i = blockIdx.x*blockDim.x + threadIdx.x;
  if (i >= total) return;
  int c = i % C;
  float m = stats[c], rstd = stats[C+c];
  float v = (h[i]-m)*rstd*g[c] + be[c];
  out[i] = fmaxf(v, 0.f);
}

// pool with BN+ReLU fused: p[g,c] = max_n relu(bn(h4[n,c]))
__global__ void k_pool(const float* __restrict__ h4, const float* __restrict__ stats,
                       const float* __restrict__ g, const float* __restrict__ be,
                       const int* __restrict__ goff, float* __restrict__ p) {
  int gph = blockIdx.x;
  int col = blockIdx.y*64 + threadIdx.x;
  int r0 = goff[gph], r1 = goff[gph+1];
  float m = stats[col], rstd = stats[1024+col];
  float scale = g[col]*rstd;
  float shift = be[col] - m*scale;
  float mx = 0.f;   // relu floor
  for (int r = r0; r < r1; ++r) {
    float v = h4[r*1024 + col]*scale + shift;
    mx = fmaxf(mx, v);
  }
  p[gph*1024 + col] = mx;
}

// ---------------- FC head (rewritten: latency-hiding) ----------------

// out[64,OUT] = A[64,K] @ W[K,OUT] + b
// grid (OUT/64, 8 row-tiles), block (64,4). A rows staged in LDS, W coalesced,
// 8 accumulators/thread for ILP, LDS reduction across the 4 k-groups.
template<int K, int OUT>
__global__ __launch_bounds__(256) void k_fc_big(
    const float* __restrict__ A, const float* __restrict__ W,
    const float* __restrict__ b, float* __restrict__ out) {
  __shared__ float As[8][K];
  __shared__ float red[4][8][64];
  int j  = blockIdx.x*64 + threadIdx.x;
  int r0 = blockIdx.y*8;
  int y  = threadIdx.y;
  for (int i = y*64 + threadIdx.x; i < 8*K; i += 256)
    As[i / K][i % K] = A[(r0 + i / K)*K + (i % K)];
  __syncthreads();
  float acc[8] = {};
  for (int k = y; k < K; k += 4) {
    float w = W[k*OUT + j];
    #pragma unroll
    for (int i = 0; i < 8; ++i) acc[i] += As[i][k] * w;
  }
  #pragma unroll
  for (int i = 0; i < 8; ++i) red[y][i][threadIdx.x] = acc[i];
  __syncthreads();
  if (y == 0) {
    float bias = b[j];
    #pragma unroll
    for (int i = 0; i < 8; ++i) {
      float v = red[0][i][threadIdx.x] + red[1][i][threadIdx.x]
              + red[2][i][threadIdx.x] + red[3][i][threadIdx.x] + bias;
      out[(r0+i)*OUT + j] = v;
    }
  }
}

// BN(train)+ReLU over [64,C], block (64 cols, 8 row-groups), grid C/64
__global__ __launch_bounds__(512) void k_bn_rows(
    float* __restrict__ h, const float* __restrict__ g,
    const float* __restrict__ be, int C) {
  int c = blockIdx.x*64 + threadIdx.x;
  int y = threadIdx.y;  // 0..7
  float v[8];
  float s = 0.f, ss = 0.f;
  #pragma unroll
  for (int i = 0; i < 8; ++i) {
    v[i] = h[(y*8+i)*C + c];
    s += v[i]; ss += v[i]*v[i];
  }
  __shared__ float rs[8][64], rss[8][64], bc[2][64];
  rs[y][threadIdx.x] = s; rss[y][threadIdx.x] = ss;
  __syncthreads();
  if (y == 0) {
    s = 0.f; ss = 0.f;
    #pragma unroll
    for (int i = 0; i < 8; ++i) { s += rs[i][threadIdx.x]; ss += rss[i][threadIdx.x]; }
    float m = s*(1.f/64.f);
    float var = ss*(1.f/64.f) - m*m;
    float rstd = rsqrtf(var + 1e-5f);
    float sc = g[c]*rstd;
    bc[0][threadIdx.x] = sc;
    bc[1][threadIdx.x] = be[c] - m*sc;
  }
  __syncthreads();
  float sc = bc[0][threadIdx.x], sh = bc[1][threadIdx.x];
  #pragma unroll
  for (int i = 0; i < 8; ++i)
    h[(y*8+i)*C + c] = fmaxf(v[i]*sc + sh, 0.f);
}

// final FC [64,256]@[256,64] + L2-normalize rows. grid 64 (1 row/block), block (64,4)
__global__ __launch_bounds__(256) void k_fc3(
    const float* __restrict__ A, const float* __restrict__ W,
    const float* __restrict__ b, float* __restrict__ out) {
  int r = blockIdx.x;
  int j = threadIdx.x, y = threadIdx.y;
  float acc = 0.f;
  #pragma unroll
  for (int kk = 0; kk < 64; ++kk) {
    int k = y*64 + kk;
    acc += A[r*256 + k] * W[k*64 + j];
  }
  __shared__ float red[4][64];
  red[y][j] = acc;
  __syncthreads();
  if (y == 0) {
    float v = red[0][j] + red[1][j] + red[2][j] + red[3][j] + b[j];
    float ss = v*v;
    #pragma unroll
    for (int off = 1; off < 64; off <<= 1) ss += __shfl_xor(ss, off);
    float inv = 1.f / fmaxf(sqrtf(ss), 1e-12f);
    out[r*64 + j] = v * inv;
  }
}

// ---------------- launch ----------------

extern "C" void kernel_launch(void* const* d_in, const int* in_sizes, int n_in,
                              void* d_out, int out_size, void* d_ws, size_t ws_size,
                              hipStream_t stream) {
  const float* x    = (const float*)d_in[0];
  const int*   ei   = (const int*)d_in[1];
  const int*   batch= (const int*)d_in[2];
  const float* W1=(const float*)d_in[3],  *b1=(const float*)d_in[4],  *g1=(const float*)d_in[5],  *be1=(const float*)d_in[6];
  const float* W2=(const float*)d_in[7],  *b2=(const float*)d_in[8],  *g2=(const float*)d_in[9],  *be2=(const float*)d_in[10];
  const float* W3=(const float*)d_in[11], *b3=(const float*)d_in[12], *g3=(const float*)d_in[13], *be3=(const float*)d_in[14];
  const float* W4=(const float*)d_in[15], *b4=(const float*)d_in[16], *g4=(const float*)d_in[17], *be4=(const float*)d_in[18];
  const float* W5=(const float*)d_in[19], *b5=(const float*)d_in[20], *g5=(const float*)d_in[21], *be5=(const float*)d_in[22];
  const float* W6=(const float*)d_in[23], *b6=(const float*)d_in[24], *g6=(const float*)d_in[25], *be6=(const float*)d_in[26];
  const float* W7=(const float*)d_in[27], *b7=(const float*)d_in[28];
  const int* esrc = ei;
  const int* edst = ei + EE;

  // workspace layout
  char* w = (char*)d_ws;
  auto alloc = [&](size_t bytes) -> void* {
    void* p = (void*)w;
    w += (bytes + 255) & ~(size_t)255;
    return p;
  };
  int*   deg     = (int*)  alloc(NN*4);
  int*   offsets = (int*)  alloc((NN+1)*4);
  int*   cursor  = (int*)  alloc(NN*4);
  int*   goff    = (int*)  alloc((GG+1)*4);
  float* dinv    = (float*)alloc(NN*4);
  int*   csr_src = (int*)  alloc((EE+NN)*4);
  float* csr_w   = (float*)alloc((EE+NN)*4);
  float* stats   = (float*)alloc(2*1024*4);
  float* agg     = (float*)alloc((size_t)NN*128*4);
  float* hbuf    = (float*)alloc((size_t)NN*128*4);
  float* hnorm   = (float*)alloc((size_t)NN*128*4);
  float* pooled  = (float*)alloc(64*1024*4);
  float* fc1     = (float*)alloc(64*512*4);
  float* fc2     = (float*)alloc(64*256*4);
  float* h4      = (float*)alloc((size_t)NN*1024*4);

  const int RPB = CDIV(NN, 64);  // stats rows per block-y

  // graph prep
  k_prep<<<CDIV(NN,256),256,0,stream>>>(deg);
  k_deg<<<CDIV(EE,256),256,0,stream>>>(edst, deg);
  k_scan<<<1,1024,0,stream>>>(deg, offsets, cursor, dinv);
  k_fill<<<CDIV(EE+NN,256),256,0,stream>>>(esrc, edst, dinv, cursor, csr_src, csr_w);
  k_goff<<<CDIV(NN,256),256,0,stream>>>(batch, goff);

  // ---- layer 1: agg(x)@W1 + b1, BN, relu ----
  k_agg<6,8,32><<<CDIV(NN,32),dim3(8,32),0,stream>>>(x, offsets, csr_src, csr_w, agg);
  k_gemm_small<6,32,32><<<NN/32,256,0,stream>>>(agg, W1, b1, hbuf);
  hipMemsetAsync(stats, 0, 2*32*4, stream);
  k_stats<<<dim3(1,64),dim3(64,4),0,stream>>>(hbuf, stats, 32, RPB);
  k_finalize<<<1,64,0,stream>>>(stats, 32, 1.f/NN);
  k_bnrelu<<<CDIV(NN*32,256),256,0,stream>>>(hbuf, stats, g1, be1, hnorm, NN*32, 32);

  // ---- layer 2 ----
  k_agg<32,32,8><<<CDIV(NN,8),dim3(32,8),0,stream>>>(hnorm, offsets, csr_src, csr_w, agg);
  k_gemm_small<32,64,16><<<NN/16,256,0,stream>>>(agg, W2, b2, hbuf);
  hipMemsetAsync(stats, 0, 2*64*4, stream);
  k_stats<<<dim3(1,64),dim3(64,4),0,stream>>>(hbuf, stats, 64, RPB);
  k_finalize<<<1,64,0,stream>>>(stats, 64, 1.f/NN);
  k_bnrelu<<<CDIV(NN*64,256),256,0,stream>>>(hbuf, stats, g2, be2, hnorm, NN*64, 64);

  // ---- layer 3 ----
  k_agg<64,64,4><<<CDIV(NN,4),dim3(64,4),0,stream>>>(hnorm, offsets, csr_src, csr_w, agg);
  k_gemm_small<64,128,16><<<NN/16,256,0,stream>>>(agg, W3, b3, hbuf);
  hipMemsetAsync(stats, 0, 2*128*4, stream);
  k_stats<<<dim3(2,64),dim3(64,4),0,stream>>>(hbuf, stats, 128, RPB);
  k_finalize<<<1,128,0,stream>>>(stats, 128, 1.f/NN);
  k_bnrelu<<<CDIV(NN*128,256),256,0,stream>>>(hbuf, stats, g3, be3, hnorm, NN*128, 128);

  // ---- layer 4 ----
  k_agg<128,128,2><<<CDIV(NN,2),dim3(128,2),0,stream>>>(hnorm, offsets, csr_src, csr_w, agg);
  k_gemm_l4<<<dim3(CDIV(NN,64),16),256,0,stream>>>(agg, W4, b4, h4);
  hipMemsetAsync(stats, 0, 2*1024*4, stream);
  k_stats<<<dim3(16,64),dim3(64,4),0,stream>>>(h4, stats, 1024, RPB);
  k_finalize<<<4,256,0,stream>>>(stats, 1024, 1.f/NN);
  // pool (BN+relu fused)
  k_pool<<<dim3(GG,16),64,0,stream>>>(h4, stats, g4, be4, goff, pooled);

  // ---- FC head ----
  k_fc_big<1024,512><<<dim3(8,8),dim3(64,4),0,stream>>>(pooled, W5, b5, fc1);
  k_bn_rows<<<8,dim3(64,8),0,stream>>>(fc1, g5, be5, 512);
  k_fc_big<512,256><<<dim3(4,8),dim3(64,4),0,stream>>>(fc1, W6, b6, fc2);
  k_bn_rows<<<4,dim3(64,8),0,stream>>>(fc2, g6, be6, 256);
  k_fc3<<<64,dim3(64,4),0,stream>>>(fc2, W7, b7, (float*)d_out);
}

// Round 4
// 632.866 us; speedup vs baseline: 1.9047x; 1.1023x over previous
//
#include <hip/hip_runtime.h>
#include <math.h>

#define NN 20000
#define EE 256000
#define GG 64
#define CDIV(a,b) (((a)+(b)-1)/(b))

// ---------------- graph preprocessing ----------------

__global__ void k_prep(int* deg) {
  int i = blockIdx.x*blockDim.x + threadIdx.x;
  if (i < NN) deg[i] = 1;   // self-loop
}

__global__ void k_deg(const int* __restrict__ dst, int* deg) {
  int i = blockIdx.x*blockDim.x + threadIdx.x;
  if (i < EE) atomicAdd(&deg[dst[i]], 1);
}

// single-block exclusive scan of deg -> offsets; also dinv, cursor
__global__ void k_scan(const int* __restrict__ deg, int* __restrict__ offsets,
                       int* __restrict__ cursor, float* __restrict__ dinv) {
  __shared__ int sums[1024];
  const int PER = 20;  // 1024*20 = 20480 >= 20000
  int t = threadIdx.x;
  int base = t * PER;
  int local[PER];
  int s = 0;
  #pragma unroll
  for (int i = 0; i < PER; ++i) {
    int idx = base + i;
    int d = (idx < NN) ? deg[idx] : 0;
    local[i] = s;
    s += d;
  }
  sums[t] = s;
  __syncthreads();
  for (int off = 1; off < 1024; off <<= 1) {
    int v = (t >= off) ? sums[t - off] : 0;
    __syncthreads();
    sums[t] += v;
    __syncthreads();
  }
  int block_excl = (t == 0) ? 0 : sums[t - 1];
  #pragma unroll
  for (int i = 0; i < PER; ++i) {
    int idx = base + i;
    if (idx < NN) {
      int off = block_excl + local[i];
      offsets[idx] = off;
      cursor[idx]  = off;
      dinv[idx] = rsqrtf((float)deg[idx]);
    }
  }
  if (t == 1023) offsets[NN] = sums[1023];
}

__global__ void k_fill(const int* __restrict__ srcv, const int* __restrict__ dstv,
                       const float* __restrict__ dinv, int* cursor,
                       int* __restrict__ csr_src, float* __restrict__ csr_w) {
  int i = blockIdx.x*blockDim.x + threadIdx.x;
  if (i < EE) {
    int s = srcv[i], d = dstv[i];
    int pos = atomicAdd(&cursor[d], 1);
    csr_src[pos] = s;
    csr_w[pos] = dinv[s] * dinv[d];
  } else if (i < EE + NN) {
    int n = i - EE;
    int pos = atomicAdd(&cursor[n], 1);
    csr_src[pos] = n;
    float di = dinv[n];
    csr_w[pos] = di * di;
  }
}

__global__ void k_goff(const int* __restrict__ batch, int* __restrict__ goff) {
  int i = blockIdx.x*blockDim.x + threadIdx.x;
  if (i >= NN) return;
  int b = batch[i];
  int bp = (i == 0) ? -1 : batch[i-1];
  for (int g = bp + 1; g <= b; ++g) goff[g] = i;
  if (i == NN-1) for (int g = b+1; g <= GG; ++g) goff[g] = NN;
}

// ---------------- aggregation: out[n,:] = sum_{e in CSR(n)} w_e * in[src_e,:] ----------------

template<int C, int TX, int TY>
__global__ void k_agg(const float* __restrict__ in, const int* __restrict__ offsets,
                      const int* __restrict__ csr_src, const float* __restrict__ csr_w,
                      float* __restrict__ out) {
  int node = blockIdx.x * TY + threadIdx.y;
  if (node >= NN) return;
  int x = threadIdx.x;
  int k0 = offsets[node], k1 = offsets[node+1];
  if (x < C) {
    float acc = 0.f;
    for (int k = k0; k < k1; ++k) {
      int s = csr_src[k];
      float w = csr_w[k];
      acc += w * in[s*C + x];
    }
    out[node*C + x] = acc;
  }
}

// ---------------- small GEMM (layers 1-3): out = A[N,K] @ W[K,OUT] + b ----------------

template<int K, int OUT, int ROWS>
__global__ __launch_bounds__(256) void k_gemm_small(
    const float* __restrict__ A, const float* __restrict__ W,
    const float* __restrict__ b, float* __restrict__ out) {
  __shared__ float Ws[K*OUT];
  __shared__ float As[ROWS*K];
  int t = threadIdx.x;
  for (int i = t; i < K*OUT; i += 256) Ws[i] = W[i];
  int row0 = blockIdx.x * ROWS;   // N divisible by ROWS
  for (int i = t; i < ROWS*K; i += 256) As[i] = A[row0*K + i];
  __syncthreads();
  const int RG  = 256 / OUT;    // row groups
  const int RPT = ROWS / RG;    // rows per thread
  int j  = t % OUT;
  int rg = t / OUT;
  float bias = b[j];
  float acc[RPT];
  #pragma unroll
  for (int i = 0; i < RPT; ++i) acc[i] = bias;
  for (int k = 0; k < K; ++k) {
    float w = Ws[k*OUT + j];
    #pragma unroll
    for (int i = 0; i < RPT; ++i)
      acc[i] += As[(rg*RPT + i)*K + k] * w;
  }
  #pragma unroll
  for (int i = 0; i < RPT; ++i)
    out[(row0 + rg*RPT + i)*OUT + j] = acc[i];
}

// ---------------- layer-4 GEMM: [20000,128] @ [128,1024] + b, fp32 tiled ----------------

__global__ __launch_bounds__(256) void k_gemm_l4(
    const float* __restrict__ A, const float* __restrict__ W,
    const float* __restrict__ bias, float* __restrict__ out) {
  __shared__ float As[64][65];
  __shared__ float Bs[64][64];
  int row0 = blockIdx.x * 64;
  int col0 = blockIdx.y * 64;
  int t = threadIdx.x;
  int tx = t % 16, ty = t / 16;
  float acc[4][4] = {};
  for (int kc = 0; kc < 128; kc += 64) {
    int lr = t / 16;
    int lc = (t % 16) * 4;
    #pragma unroll
    for (int rr = 0; rr < 64; rr += 16) {
      int r = row0 + rr + lr;
      float4 v = make_float4(0.f,0.f,0.f,0.f);
      if (r < NN) v = *(const float4*)&A[r*128 + kc + lc];
      As[rr+lr][lc+0]=v.x; As[rr+lr][lc+1]=v.y; As[rr+lr][lc+2]=v.z; As[rr+lr][lc+3]=v.w;
    }
    #pragma unroll
    for (int rr = 0; rr < 64; rr += 16) {
      float4 v = *(const float4*)&W[(kc+rr+lr)*1024 + col0 + lc];
      *(float4*)&Bs[rr+lr][lc] = v;
    }
    __syncthreads();
    #pragma unroll
    for (int kk = 0; kk < 64; ++kk) {
      float a[4], bv[4];
      #pragma unroll
      for (int i=0;i<4;++i) a[i] = As[ty*4+i][kk];
      #pragma unroll
      for (int j=0;j<4;++j) bv[j] = Bs[kk][tx*4+j];
      #pragma unroll
      for (int i=0;i<4;++i)
        #pragma unroll
        for (int j=0;j<4;++j)
          acc[i][j] += a[i]*bv[j];
    }
    __syncthreads();
  }
  float4 bv = *(const float4*)&bias[col0 + tx*4];
  #pragma unroll
  for (int i=0;i<4;++i) {
    int r = row0 + ty*4 + i;
    if (r < NN) {
      float4 o = make_float4(acc[i][0]+bv.x, acc[i][1]+bv.y, acc[i][2]+bv.z, acc[i][3]+bv.w);
      *(float4*)&out[r*1024 + col0 + tx*4] = o;
    }
  }
}

// ---------------- batchnorm pieces ----------------

__global__ void k_stats(const float* __restrict__ h, float* __restrict__ stats,
                        int C, int rows_per_block) {
  int c = blockIdx.x*64 + threadIdx.x;
  int r0 = blockIdx.y * rows_per_block;
  int r1 = min(NN, r0 + rows_per_block);
  float s = 0.f, ss = 0.f;
  if (c < C) {
    for (int r = r0 + threadIdx.y; r < r1; r += 4) {
      float v = h[r*C + c];
      s += v; ss += v*v;
    }
  }
  __shared__ float red[2][4][64];
  red[0][threadIdx.y][threadIdx.x] = s;
  red[1][threadIdx.y][threadIdx.x] = ss;
  __syncthreads();
  if (threadIdx.y == 0 && c < C) {
    s  = red[0][0][threadIdx.x]+red[0][1][threadIdx.x]+red[0][2][threadIdx.x]+red[0][3][threadIdx.x];
    ss = red[1][0][threadIdx.x]+red[1][1][threadIdx.x]+red[1][2][threadIdx.x]+red[1][3][threadIdx.x];
    atomicAdd(&stats[c], s);
    atomicAdd(&stats[C+c], ss);
  }
}

__global__ void k_finalize(float* stats, int C, float invN) {
  int c = blockIdx.x*blockDim.x + threadIdx.x;
  if (c < C) {
    float m = stats[c] * invN;
    float v = stats[C+c]*invN - m*m;
    stats[c] = m;
    stats[C+c] = rsqrtf(v + 1e-5f);
  }
}

__global__ void k_bnrelu(const float* __restrict__ h, const float* __restrict__ stats,
                         const float* __restrict__ g, const float* __restrict__ be,
                         float* __restrict__ out, int total, int C) {
  int i = blockIdx.x*blockDim.x + threadIdx.x;
  if (i >= total) return;
  int c = i % C;
  float m = stats[c], rstd = stats[C+c];
  float v = (h[i]-m)*rstd*g[c] + be[c];
  out[i] = fmaxf(v, 0.f);
}

// pool with BN+ReLU fused: p[g,c] = max_n relu(bn(h4[n,c]))
__global__ void k_pool(const float* __restrict__ h4, const float* __restrict__ stats,
                       const float* __restrict__ g, const float* __restrict__ be,
                       const int* __restrict__ goff, float* __restrict__ p) {
  int gph = blockIdx.x;
  int col = blockIdx.y*64 + threadIdx.x;
  int r0 = goff[gph], r1 = goff[gph+1];
  float m = stats[col], rstd = stats[1024+col];
  float scale = g[col]*rstd;
  float shift = be[col] - m*scale;
  float mx = 0.f;   // relu floor
  for (int r = r0; r < r1; ++r) {
    float v = h4[r*1024 + col]*scale + shift;
    mx = fmaxf(mx, v);
  }
  p[gph*1024 + col] = mx;
}

// ---------------- FC head: K-split LDS-tiled GEMM + atomics ----------------

__global__ void k_bias_init(float* __restrict__ out, const float* __restrict__ b, int OUT) {
  int i = blockIdx.x*blockDim.x + threadIdx.x;
  if (i < 64*OUT) out[i] = b[i % OUT];
}

// out[64,OUT] += A[64,k-slice] @ W[k-slice,OUT]
// grid (OUT/64, K/KT), block (64,4). LDS-staged, 16 outputs/thread.
template<int K, int OUT, int KT>
__global__ __launch_bounds__(256) void k_fc_tile(
    const float* __restrict__ A, const float* __restrict__ W,
    float* __restrict__ out) {
  __shared__ float As[64][KT];
  __shared__ float Ws[KT][64];
  int t = threadIdx.y*64 + threadIdx.x;
  int j0 = blockIdx.x*64;
  int k0 = blockIdx.y*KT;
  // stage A-tile: 64 rows x KT cols, float4 loads
  #pragma unroll 4
  for (int i = t; i < 64*KT/4; i += 256) {
    int r  = i / (KT/4);
    int c4 = i % (KT/4);
    float4 v = *(const float4*)&A[r*K + k0 + c4*4];
    *(float4*)&As[r][c4*4] = v;
  }
  // stage W-tile: KT rows x 64 cols
  #pragma unroll 4
  for (int i = t; i < KT*16; i += 256) {
    int k  = i / 16;
    int c4 = i % 16;
    float4 v = *(const float4*)&W[(k0+k)*OUT + j0 + c4*4];
    *(float4*)&Ws[k][c4*4] = v;
  }
  __syncthreads();
  int j  = threadIdx.x;
  int r0 = threadIdx.y*16;
  float acc[16] = {};
  for (int kk = 0; kk < KT; ++kk) {
    float w = Ws[kk][j];   // consecutive across lanes, conflict-free
    #pragma unroll
    for (int i = 0; i < 16; ++i) acc[i] += As[r0+i][kk] * w;  // broadcast
  }
  #pragma unroll
  for (int i = 0; i < 16; ++i) atomicAdd(&out[(r0+i)*OUT + j0 + j], acc[i]);
}

// BN(train)+ReLU over [64,C], block (64 cols, 8 row-groups), grid C/64
__global__ __launch_bounds__(512) void k_bn_rows(
    float* __restrict__ h, const float* __restrict__ g,
    const float* __restrict__ be, int C) {
  int c = blockIdx.x*64 + threadIdx.x;
  int y = threadIdx.y;  // 0..7
  float v[8];
  float s = 0.f, ss = 0.f;
  #pragma unroll
  for (int i = 0; i < 8; ++i) {
    v[i] = h[(y*8+i)*C + c];
    s += v[i]; ss += v[i]*v[i];
  }
  __shared__ float rs[8][64], rss[8][64], bc[2][64];
  rs[y][threadIdx.x] = s; rss[y][threadIdx.x] = ss;
  __syncthreads();
  if (y == 0) {
    s = 0.f; ss = 0.f;
    #pragma unroll
    for (int i = 0; i < 8; ++i) { s += rs[i][threadIdx.x]; ss += rss[i][threadIdx.x]; }
    float m = s*(1.f/64.f);
    float var = ss*(1.f/64.f) - m*m;
    float rstd = rsqrtf(var + 1e-5f);
    float sc = g[c]*rstd;
    bc[0][threadIdx.x] = sc;
    bc[1][threadIdx.x] = be[c] - m*sc;
  }
  __syncthreads();
  float sc = bc[0][threadIdx.x], sh = bc[1][threadIdx.x];
  #pragma unroll
  for (int i = 0; i < 8; ++i)
    h[(y*8+i)*C + c] = fmaxf(v[i]*sc + sh, 0.f);
}

// L2-normalize rows of [64,64]
__global__ void k_l2norm(const float* __restrict__ in, float* __restrict__ out) {
  int r = blockIdx.x, j = threadIdx.x;
  float v = in[r*64 + j];
  float ss = v*v;
  #pragma unroll
  for (int off = 1; off < 64; off <<= 1) ss += __shfl_xor(ss, off);
  float inv = 1.f / fmaxf(sqrtf(ss), 1e-12f);
  out[r*64 + j] = v * inv;
}

// ---------------- launch ----------------

extern "C" void kernel_launch(void* const* d_in, const int* in_sizes, int n_in,
                              void* d_out, int out_size, void* d_ws, size_t ws_size,
                              hipStream_t stream) {
  const float* x    = (const float*)d_in[0];
  const int*   ei   = (const int*)d_in[1];
  const int*   batch= (const int*)d_in[2];
  const float* W1=(const float*)d_in[3],  *b1=(const float*)d_in[4],  *g1=(const float*)d_in[5],  *be1=(const float*)d_in[6];
  const float* W2=(const float*)d_in[7],  *b2=(const float*)d_in[8],  *g2=(const float*)d_in[9],  *be2=(const float*)d_in[10];
  const float* W3=(const float*)d_in[11], *b3=(const float*)d_in[12], *g3=(const float*)d_in[13], *be3=(const float*)d_in[14];
  const float* W4=(const float*)d_in[15], *b4=(const float*)d_in[16], *g4=(const float*)d_in[17], *be4=(const float*)d_in[18];
  const float* W5=(const float*)d_in[19], *b5=(const float*)d_in[20], *g5=(const float*)d_in[21], *be5=(const float*)d_in[22];
  const float* W6=(const float*)d_in[23], *b6=(const float*)d_in[24], *g6=(const float*)d_in[25], *be6=(const float*)d_in[26];
  const float* W7=(const float*)d_in[27], *b7=(const float*)d_in[28];
  const int* esrc = ei;
  const int* edst = ei + EE;

  // workspace layout
  char* w = (char*)d_ws;
  auto alloc = [&](size_t bytes) -> void* {
    void* p = (void*)w;
    w += (bytes + 255) & ~(size_t)255;
    return p;
  };
  int*   deg     = (int*)  alloc(NN*4);
  int*   offsets = (int*)  alloc((NN+1)*4);
  int*   cursor  = (int*)  alloc(NN*4);
  int*   goff    = (int*)  alloc((GG+1)*4);
  float* dinv    = (float*)alloc(NN*4);
  int*   csr_src = (int*)  alloc((EE+NN)*4);
  float* csr_w   = (float*)alloc((EE+NN)*4);
  float* stats   = (float*)alloc(2*1024*4);
  float* agg     = (float*)alloc((size_t)NN*128*4);
  float* hbuf    = (float*)alloc((size_t)NN*128*4);
  float* hnorm   = (float*)alloc((size_t)NN*128*4);
  float* pooled  = (float*)alloc(64*1024*4);
  float* fc1     = (float*)alloc(64*512*4);
  float* fc2     = (float*)alloc(64*256*4);
  float* fc3raw  = (float*)alloc(64*64*4);
  float* h4      = (float*)alloc((size_t)NN*1024*4);

  const int RPB = CDIV(NN, 64);  // stats rows per block-y

  // graph prep
  k_prep<<<CDIV(NN,256),256,0,stream>>>(deg);
  k_deg<<<CDIV(EE,256),256,0,stream>>>(edst, deg);
  k_scan<<<1,1024,0,stream>>>(deg, offsets, cursor, dinv);
  k_fill<<<CDIV(EE+NN,256),256,0,stream>>>(esrc, edst, dinv, cursor, csr_src, csr_w);
  k_goff<<<CDIV(NN,256),256,0,stream>>>(batch, goff);

  // ---- layer 1: agg(x)@W1 + b1, BN, relu ----
  k_agg<6,8,32><<<CDIV(NN,32),dim3(8,32),0,stream>>>(x, offsets, csr_src, csr_w, agg);
  k_gemm_small<6,32,32><<<NN/32,256,0,stream>>>(agg, W1, b1, hbuf);
  hipMemsetAsync(stats, 0, 2*32*4, stream);
  k_stats<<<dim3(1,64),dim3(64,4),0,stream>>>(hbuf, stats, 32, RPB);
  k_finalize<<<1,64,0,stream>>>(stats, 32, 1.f/NN);
  k_bnrelu<<<CDIV(NN*32,256),256,0,stream>>>(hbuf, stats, g1, be1, hnorm, NN*32, 32);

  // ---- layer 2 ----
  k_agg<32,32,8><<<CDIV(NN,8),dim3(32,8),0,stream>>>(hnorm, offsets, csr_src, csr_w, agg);
  k_gemm_small<32,64,16><<<NN/16,256,0,stream>>>(agg, W2, b2, hbuf);
  hipMemsetAsync(stats, 0, 2*64*4, stream);
  k_stats<<<dim3(1,64),dim3(64,4),0,stream>>>(hbuf, stats, 64, RPB);
  k_finalize<<<1,64,0,stream>>>(stats, 64, 1.f/NN);
  k_bnrelu<<<CDIV(NN*64,256),256,0,stream>>>(hbuf, stats, g2, be2, hnorm, NN*64, 64);

  // ---- layer 3 ----
  k_agg<64,64,4><<<CDIV(NN,4),dim3(64,4),0,stream>>>(hnorm, offsets, csr_src, csr_w, agg);
  k_gemm_small<64,128,16><<<NN/16,256,0,stream>>>(agg, W3, b3, hbuf);
  hipMemsetAsync(stats, 0, 2*128*4, stream);
  k_stats<<<dim3(2,64),dim3(64,4),0,stream>>>(hbuf, stats, 128, RPB);
  k_finalize<<<1,128,0,stream>>>(stats, 128, 1.f/NN);
  k_bnrelu<<<CDIV(NN*128,256),256,0,stream>>>(hbuf, stats, g3, be3, hnorm, NN*128, 128);

  // ---- layer 4 ----
  k_agg<128,128,2><<<CDIV(NN,2),dim3(128,2),0,stream>>>(hnorm, offsets, csr_src, csr_w, agg);
  k_gemm_l4<<<dim3(CDIV(NN,64),16),256,0,stream>>>(agg, W4, b4, h4);
  hipMemsetAsync(stats, 0, 2*1024*4, stream);
  k_stats<<<dim3(16,64),dim3(64,4),0,stream>>>(h4, stats, 1024, RPB);
  k_finalize<<<4,256,0,stream>>>(stats, 1024, 1.f/NN);
  // pool (BN+relu fused)
  k_pool<<<dim3(GG,16),64,0,stream>>>(h4, stats, g4, be4, goff, pooled);

  // ---- FC head ----
  k_bias_init<<<CDIV(64*512,256),256,0,stream>>>(fc1, b5, 512);
  k_fc_tile<1024,512,128><<<dim3(8,8),dim3(64,4),0,stream>>>(pooled, W5, fc1);
  k_bn_rows<<<8,dim3(64,8),0,stream>>>(fc1, g5, be5, 512);

  k_bias_init<<<CDIV(64*256,256),256,0,stream>>>(fc2, b6, 256);
  k_fc_tile<512,256,128><<<dim3(4,4),dim3(64,4),0,stream>>>(fc1, W6, fc2);
  k_bn_rows<<<4,dim3(64,8),0,stream>>>(fc2, g6, be6, 256);

  k_bias_init<<<CDIV(64*64,256),256,0,stream>>>(fc3raw, b7, 64);
  k_fc_tile<256,64,64><<<dim3(1,4),dim3(64,4),0,stream>>>(fc2, W7, fc3raw);
  k_l2norm<<<64,64,0,stream>>>(fc3raw, (float*)d_out);
}

// Round 5
// 569.721 us; speedup vs baseline: 2.1158x; 1.1108x over previous
//
#include <hip/hip_runtime.h>
#include <math.h>

#define NN 20000
#define EE 256000
#define GG 64
#define CDIV(a,b) (((a)+(b)-1)/(b))

typedef __attribute__((ext_vector_type(8))) short bf16x8;
typedef __attribute__((ext_vector_type(4))) float f32x4;

__device__ __forceinline__ unsigned fkey(float f) {
  unsigned u = __float_as_uint(f);
  return (u & 0x80000000u) ? ~u : (u | 0x80000000u);
}
__device__ __forceinline__ float fdec(unsigned k) {
  unsigned u = (k & 0x80000000u) ? (k ^ 0x80000000u) : ~k;
  return __uint_as_float(u);
}
__device__ __forceinline__ unsigned short rne_bf16(float f) {
  unsigned u = __float_as_uint(f);
  unsigned r = (u + 0x7fffu + ((u >> 16) & 1u)) >> 16;
  return (unsigned short)r;
}

// ---------------- graph preprocessing ----------------

__global__ void k_prep(int* deg) {
  int i = blockIdx.x*blockDim.x + threadIdx.x;
  if (i < NN) deg[i] = 1;   // self-loop
}

__global__ void k_deg(const int* __restrict__ dst, int* deg) {
  int i = blockIdx.x*blockDim.x + threadIdx.x;
  if (i < EE) atomicAdd(&deg[dst[i]], 1);
}

__global__ void k_scan(const int* __restrict__ deg, int* __restrict__ offsets,
                       int* __restrict__ cursor, float* __restrict__ dinv) {
  __shared__ int sums[1024];
  const int PER = 20;
  int t = threadIdx.x;
  int base = t * PER;
  int local[PER];
  int s = 0;
  #pragma unroll
  for (int i = 0; i < PER; ++i) {
    int idx = base + i;
    int d = (idx < NN) ? deg[idx] : 0;
    local[i] = s;
    s += d;
  }
  sums[t] = s;
  __syncthreads();
  for (int off = 1; off < 1024; off <<= 1) {
    int v = (t >= off) ? sums[t - off] : 0;
    __syncthreads();
    sums[t] += v;
    __syncthreads();
  }
  int block_excl = (t == 0) ? 0 : sums[t - 1];
  #pragma unroll
  for (int i = 0; i < PER; ++i) {
    int idx = base + i;
    if (idx < NN) {
      int off = block_excl + local[i];
      offsets[idx] = off;
      cursor[idx]  = off;
      dinv[idx] = rsqrtf((float)deg[idx]);
    }
  }
  if (t == 1023) offsets[NN] = sums[1023];
}

__global__ void k_fill(const int* __restrict__ srcv, const int* __restrict__ dstv,
                       const float* __restrict__ dinv, int* cursor,
                       int* __restrict__ csr_src, float* __restrict__ csr_w) {
  int i = blockIdx.x*blockDim.x + threadIdx.x;
  if (i < EE) {
    int s = srcv[i], d = dstv[i];
    int pos = atomicAdd(&cursor[d], 1);
    csr_src[pos] = s;
    csr_w[pos] = dinv[s] * dinv[d];
  } else if (i < EE + NN) {
    int n = i - EE;
    int pos = atomicAdd(&cursor[n], 1);
    csr_src[pos] = n;
    float di = dinv[n];
    csr_w[pos] = di * di;
  }
}

__global__ void k_goff(const int* __restrict__ batch, int* __restrict__ goff) {
  int i = blockIdx.x*blockDim.x + threadIdx.x;
  if (i >= NN) return;
  int b = batch[i];
  int bp = (i == 0) ? -1 : batch[i-1];
  for (int g = bp + 1; g <= b; ++g) goff[g] = i;
  if (i == NN-1) for (int g = b+1; g <= GG; ++g) goff[g] = NN;
}

// ---------------- aggregation ----------------

template<int C, int TX, int TY>
__global__ void k_agg(const float* __restrict__ in, const int* __restrict__ offsets,
                      const int* __restrict__ csr_src, const float* __restrict__ csr_w,
                      float* __restrict__ out) {
  int node = blockIdx.x * TY + threadIdx.y;
  if (node >= NN) return;
  int x = threadIdx.x;
  int k0 = offsets[node], k1 = offsets[node+1];
  if (x < C) {
    float acc = 0.f;
    for (int k = k0; k < k1; ++k) {
      int s = csr_src[k];
      float w = csr_w[k];
      acc += w * in[s*C + x];
    }
    out[node*C + x] = acc;
  }
}

// layer-4 aggregation, emits bf16 directly
__global__ void k_agg_bf(const float* __restrict__ in, const int* __restrict__ offsets,
                         const int* __restrict__ csr_src, const float* __restrict__ csr_w,
                         unsigned short* __restrict__ out) {
  int node = blockIdx.x * 2 + threadIdx.y;
  if (node >= NN) return;
  int x = threadIdx.x;  // 0..127
  int k0 = offsets[node], k1 = offsets[node+1];
  float acc = 0.f;
  for (int k = k0; k < k1; ++k) {
    int s = csr_src[k];
    float w = csr_w[k];
    acc += w * in[s*128 + x];
  }
  out[node*128 + x] = rne_bf16(acc);
}

// W4 [128,1024] fp32 -> Wt [1024,128] bf16
__global__ void k_wprep(const float* __restrict__ W, unsigned short* __restrict__ out) {
  int i = blockIdx.x*256 + threadIdx.x;
  if (i >= 128*1024) return;
  int k = i >> 10, c = i & 1023;
  out[c*128 + k] = rne_bf16(W[i]);
}

// ---------------- small GEMM (layers 1-3) ----------------

template<int K, int OUT, int ROWS>
__global__ __launch_bounds__(256) void k_gemm_small(
    const float* __restrict__ A, const float* __restrict__ W,
    const float* __restrict__ b, float* __restrict__ out) {
  __shared__ float Ws[K*OUT];
  __shared__ float As[ROWS*K];
  int t = threadIdx.x;
  for (int i = t; i < K*OUT; i += 256) Ws[i] = W[i];
  int row0 = blockIdx.x * ROWS;
  for (int i = t; i < ROWS*K; i += 256) As[i] = A[row0*K + i];
  __syncthreads();
  const int RG  = 256 / OUT;
  const int RPT = ROWS / RG;
  int j  = t % OUT;
  int rg = t / OUT;
  float bias = b[j];
  float acc[RPT];
  #pragma unroll
  for (int i = 0; i < RPT; ++i) acc[i] = bias;
  for (int k = 0; k < K; ++k) {
    float w = Ws[k*OUT + j];
    #pragma unroll
    for (int i = 0; i < RPT; ++i)
      acc[i] += As[(rg*RPT + i)*K + k] * w;
  }
  #pragma unroll
  for (int i = 0; i < RPT; ++i)
    out[(row0 + rg*RPT + i)*OUT + j] = acc[i];
}

// ---------------- layer-4: bf16 MFMA GEMM with fused stats+pool epilogue ----------------
// A_bf [NN,128] bf16, Bt [1024,128] bf16 (W4 transposed). 128x128 tile, 4 waves (2x2).
// Epilogue: h = D + b4; per-column sum/sumsq atomics; per-graph per-column max/min atomics.
// h4 is never materialized.

__global__ __launch_bounds__(256) void k_gemm_l4_mfma(
    const unsigned short* __restrict__ A, const unsigned short* __restrict__ Bt,
    const float* __restrict__ bias, const int* __restrict__ batch,
    float* __restrict__ stats, unsigned* __restrict__ pmax, unsigned* __restrict__ pmin) {
  __shared__ unsigned short As[128*128];   // 32 KB, chunk-swizzled
  __shared__ unsigned short Bs[128*128];   // 32 KB
  int t = threadIdx.x;
  int row0 = blockIdx.x * 128;
  int col0 = blockIdx.y * 128;
  // stage A (guarded) — 16B chunks, chunk' = ck ^ (row&7)
  #pragma unroll
  for (int j = 0; j < 8; ++j) {
    int c = j*256 + t;
    int r = c >> 4, ck = c & 15;
    int rg = row0 + r;
    ulonglong2 v; v.x = 0; v.y = 0;
    if (rg < NN) v = *(const ulonglong2*)&A[rg*128 + ck*8];
    *(ulonglong2*)&As[r*128 + (ck ^ (r & 7))*8] = v;
  }
  // stage Bt
  #pragma unroll
  for (int j = 0; j < 8; ++j) {
    int c = j*256 + t;
    int r = c >> 4, ck = c & 15;
    ulonglong2 v = *(const ulonglong2*)&Bt[(col0 + r)*128 + ck*8];
    *(ulonglong2*)&Bs[r*128 + (ck ^ (r & 7))*8] = v;
  }
  __syncthreads();

  int w = t >> 6, l = t & 63;
  int wr = w >> 1, wc = w & 1;
  int lrow = l & 15, lk = l >> 4;
  f32x4 acc[4][4] = {};
  #pragma unroll
  for (int ks = 0; ks < 4; ++ks) {
    int kc = ks*4 + lk;
    bf16x8 a[4], b[4];
    #pragma unroll
    for (int m = 0; m < 4; ++m) {
      int r = wr*64 + m*16 + lrow;
      a[m] = *(const bf16x8*)&As[r*128 + (kc ^ (r & 7))*8];
    }
    #pragma unroll
    for (int n = 0; n < 4; ++n) {
      int r = wc*64 + n*16 + lrow;
      b[n] = *(const bf16x8*)&Bs[r*128 + (kc ^ (r & 7))*8];
    }
    #pragma unroll
    for (int m = 0; m < 4; ++m)
      #pragma unroll
      for (int n = 0; n < 4; ++n)
        acc[m][n] = __builtin_amdgcn_mfma_f32_16x16x32_bf16(a[m], b[n], acc[m][n], 0, 0, 0);
  }

  // ---- epilogue ----
  int rbase = row0 + wr*64;
  float bias_n[4];
  #pragma unroll
  for (int n = 0; n < 4; ++n) bias_n[n] = bias[col0 + wc*64 + n*16 + lrow];

  float s[4] = {}, ss[4] = {};
  float mx[4], mn[4];
  #pragma unroll
  for (int n = 0; n < 4; ++n) { mx[n] = -3.4e38f; mn[n] = 3.4e38f; }
  #pragma unroll
  for (int m = 0; m < 4; ++m)
    #pragma unroll
    for (int r = 0; r < 4; ++r) {
      int row_g = rbase + m*16 + lk*4 + r;
      if (row_g < NN) {
        #pragma unroll
        for (int n = 0; n < 4; ++n) {
          float v = acc[m][n][r] + bias_n[n];
          s[n] += v; ss[n] += v*v;
          mx[n] = fmaxf(mx[n], v); mn[n] = fminf(mn[n], v);
        }
      }
    }
  // column totals across lane groups (rows): lanes l, l+16, l+32, l+48 share col
  #pragma unroll
  for (int n = 0; n < 4; ++n) {
    s[n]  += __shfl_xor(s[n], 16);  s[n]  += __shfl_xor(s[n], 32);
    ss[n] += __shfl_xor(ss[n], 16); ss[n] += __shfl_xor(ss[n], 32);
  }
  if (l < 16) {
    #pragma unroll
    for (int n = 0; n < 4; ++n) {
      int cg = col0 + wc*64 + n*16 + l;
      atomicAdd(&stats[cg], s[n]);
      atomicAdd(&stats[1024 + cg], ss[n]);
    }
  }
  // pool: per-graph raw max/min
  if (rbase < NN) {
    int rlast = min(rbase + 63, NN - 1);
    int glo = batch[rbase], ghi = batch[rlast];
    if (glo == ghi) {
      #pragma unroll
      for (int n = 0; n < 4; ++n) {
        mx[n] = fmaxf(mx[n], __shfl_xor(mx[n], 16)); mx[n] = fmaxf(mx[n], __shfl_xor(mx[n], 32));
        mn[n] = fminf(mn[n], __shfl_xor(mn[n], 16)); mn[n] = fminf(mn[n], __shfl_xor(mn[n], 32));
      }
      if (l < 16) {
        #pragma unroll
        for (int n = 0; n < 4; ++n) {
          int cg = col0 + wc*64 + n*16 + l;
          atomicMax(&pmax[glo*1024 + cg], fkey(mx[n]));
          atomicMin(&pmin[glo*1024 + cg], fkey(mn[n]));
        }
      }
    } else {
      // graph boundary inside this wave's rows: per-value atomics (rare)
      #pragma unroll
      for (int m = 0; m < 4; ++m)
        #pragma unroll
        for (int r = 0; r < 4; ++r) {
          int row_g = rbase + m*16 + lk*4 + r;
          if (row_g < NN) {
            int g = batch[row_g];
            #pragma unroll
            for (int n = 0; n < 4; ++n) {
              float v = acc[m][n][r] + bias_n[n];
              int cg = col0 + wc*64 + n*16 + lrow;
              atomicMax(&pmax[g*1024 + cg], fkey(v));
              atomicMin(&pmin[g*1024 + cg], fkey(v));
            }
          }
        }
    }
  }
}

// ---------------- batchnorm pieces (layers 1-3) ----------------

__global__ void k_stats(const float* __restrict__ h, float* __restrict__ stats,
                        int C, int rows_per_block) {
  int c = blockIdx.x*64 + threadIdx.x;
  int r0 = blockIdx.y * rows_per_block;
  int r1 = min(NN, r0 + rows_per_block);
  float s = 0.f, ss = 0.f;
  if (c < C) {
    for (int r = r0 + threadIdx.y; r < r1; r += 4) {
      float v = h[r*C + c];
      s += v; ss += v*v;
    }
  }
  __shared__ float red[2][4][64];
  red[0][threadIdx.y][threadIdx.x] = s;
  red[1][threadIdx.y][threadIdx.x] = ss;
  __syncthreads();
  if (threadIdx.y == 0 && c < C) {
    s  = red[0][0][threadIdx.x]+red[0][1][threadIdx.x]+red[0][2][threadIdx.x]+red[0][3][threadIdx.x];
    ss = red[1][0][threadIdx.x]+red[1][1][threadIdx.x]+red[1][2][threadIdx.x]+red[1][3][threadIdx.x];
    atomicAdd(&stats[c], s);
    atomicAdd(&stats[C+c], ss);
  }
}

__global__ void k_finalize(float* stats, int C, float invN) {
  int c = blockIdx.x*blockDim.x + threadIdx.x;
  if (c < C) {
    float m = stats[c] * invN;
    float v = stats[C+c]*invN - m*m;
    stats[c] = m;
    stats[C+c] = rsqrtf(v + 1e-5f);
  }
}

__global__ void k_bnrelu(const float* __restrict__ h, const float* __restrict__ stats,
                         const float* __restrict__ g, const float* __restrict__ be,
                         float* __restrict__ out, int total, int C) {
  int i = blockIdx.x*blockDim.x + threadIdx.x;
  if (i >= total) return;
  int c = i % C;
  float m = stats[c], rstd = stats[C+c];
  float v = (h[i]-m)*rstd*g[c] + be[c];
  out[i] = fmaxf(v, 0.f);
}

// apply BN+relu to pooled raw max/min [64,1024]
__global__ void k_bnpool(const unsigned* __restrict__ pmax, const unsigned* __restrict__ pmin,
                         const float* __restrict__ stats, const float* __restrict__ g,
                         const float* __restrict__ be, float* __restrict__ p) {
  int i = blockIdx.x*256 + threadIdx.x;
  if (i >= 64*1024) return;
  int c = i & 1023;
  float mean = stats[c], rstd = stats[1024+c];
  float sc = g[c]*rstd, sh = be[c] - mean*sc;
  float v = (sc >= 0.f) ? fdec(pmax[i]) : fdec(pmin[i]);
  p[i] = fmaxf(v*sc + sh, 0.f);
}

// ---------------- FC head: K-split LDS-tiled GEMM + atomics ----------------

__global__ void k_bias_init(float* __restrict__ out, const float* __restrict__ b, int OUT) {
  int i = blockIdx.x*blockDim.x + threadIdx.x;
  if (i < 64*OUT) out[i] = b[i % OUT];
}

template<int K, int OUT, int KT>
__global__ __launch_bounds__(256) void k_fc_tile(
    const float* __restrict__ A, const float* __restrict__ W,
    float* __restrict__ out) {
  __shared__ float As[64][KT];
  __shared__ float Ws[KT][64];
  int t = threadIdx.y*64 + threadIdx.x;
  int j0 = blockIdx.x*64;
  int k0 = blockIdx.y*KT;
  #pragma unroll 4
  for (int i = t; i < 64*KT/4; i += 256) {
    int r  = i / (KT/4);
    int c4 = i % (KT/4);
    float4 v = *(const float4*)&A[r*K + k0 + c4*4];
    *(float4*)&As[r][c4*4] = v;
  }
  #pragma unroll 4
  for (int i = t; i < KT*16; i += 256) {
    int k  = i / 16;
    int c4 = i % 16;
    float4 v = *(const float4*)&W[(k0+k)*OUT + j0 + c4*4];
    *(float4*)&Ws[k][c4*4] = v;
  }
  __syncthreads();
  int j  = threadIdx.x;
  int r0 = threadIdx.y*16;
  float acc[16] = {};
  for (int kk = 0; kk < KT; ++kk) {
    float w = Ws[kk][j];
    #pragma unroll
    for (int i = 0; i < 16; ++i) acc[i] += As[r0+i][kk] * w;
  }
  #pragma unroll
  for (int i = 0; i < 16; ++i) atomicAdd(&out[(r0+i)*OUT + j0 + j], acc[i]);
}

__global__ __launch_bounds__(512) void k_bn_rows(
    float* __restrict__ h, const float* __restrict__ g,
    const float* __restrict__ be, int C) {
  int c = blockIdx.x*64 + threadIdx.x;
  int y = threadIdx.y;
  float v[8];
  float s = 0.f, ss = 0.f;
  #pragma unroll
  for (int i = 0; i < 8; ++i) {
    v[i] = h[(y*8+i)*C + c];
    s += v[i]; ss += v[i]*v[i];
  }
  __shared__ float rs[8][64], rss[8][64], bc[2][64];
  rs[y][threadIdx.x] = s; rss[y][threadIdx.x] = ss;
  __syncthreads();
  if (y == 0) {
    s = 0.f; ss = 0.f;
    #pragma unroll
    for (int i = 0; i < 8; ++i) { s += rs[i][threadIdx.x]; ss += rss[i][threadIdx.x]; }
    float m = s*(1.f/64.f);
    float var = ss*(1.f/64.f) - m*m;
    float rstd = rsqrtf(var + 1e-5f);
    float sc = g[c]*rstd;
    bc[0][threadIdx.x] = sc;
    bc[1][threadIdx.x] = be[c] - m*sc;
  }
  __syncthreads();
  float sc = bc[0][threadIdx.x], sh = bc[1][threadIdx.x];
  #pragma unroll
  for (int i = 0; i < 8; ++i)
    h[(y*8+i)*C + c] = fmaxf(v[i]*sc + sh, 0.f);
}

__global__ void k_l2norm(const float* __restrict__ in, float* __restrict__ out) {
  int r = blockIdx.x, j = threadIdx.x;
  float v = in[r*64 + j];
  float ss = v*v;
  #pragma unroll
  for (int off = 1; off < 64; off <<= 1) ss += __shfl_xor(ss, off);
  float inv = 1.f / fmaxf(sqrtf(ss), 1e-12f);
  out[r*64 + j] = v * inv;
}

// ---------------- launch ----------------

extern "C" void kernel_launch(void* const* d_in, const int* in_sizes, int n_in,
                              void* d_out, int out_size, void* d_ws, size_t ws_size,
                              hipStream_t stream) {
  const float* x    = (const float*)d_in[0];
  const int*   ei   = (const int*)d_in[1];
  const int*   batch= (const int*)d_in[2];
  const float* W1=(const float*)d_in[3],  *b1=(const float*)d_in[4],  *g1=(const float*)d_in[5],  *be1=(const float*)d_in[6];
  const float* W2=(const float*)d_in[7],  *b2=(const float*)d_in[8],  *g2=(const float*)d_in[9],  *be2=(const float*)d_in[10];
  const float* W3=(const float*)d_in[11], *b3=(const float*)d_in[12], *g3=(const float*)d_in[13], *be3=(const float*)d_in[14];
  const float* W4=(const float*)d_in[15], *b4=(const float*)d_in[16], *g4=(const float*)d_in[17], *be4=(const float*)d_in[18];
  const float* W5=(const float*)d_in[19], *b5=(const float*)d_in[20], *g5=(const float*)d_in[21], *be5=(const float*)d_in[22];
  const float* W6=(const float*)d_in[23], *b6=(const float*)d_in[24], *g6=(const float*)d_in[25], *be6=(const float*)d_in[26];
  const float* W7=(const float*)d_in[27], *b7=(const float*)d_in[28];
  const int* esrc = ei;
  const int* edst = ei + EE;

  char* w = (char*)d_ws;
  auto alloc = [&](size_t bytes) -> void* {
    void* p = (void*)w;
    w += (bytes + 255) & ~(size_t)255;
    return p;
  };
  int*   deg     = (int*)  alloc(NN*4);
  int*   offsets = (int*)  alloc((NN+1)*4);
  int*   cursor  = (int*)  alloc(NN*4);
  int*   goff    = (int*)  alloc((GG+1)*4);
  float* dinv    = (float*)alloc(NN*4);
  int*   csr_src = (int*)  alloc((EE+NN)*4);
  float* csr_w   = (float*)alloc((EE+NN)*4);
  float* stats   = (float*)alloc(2*1024*4);
  float* agg     = (float*)alloc((size_t)NN*128*4);
  float* hbuf    = (float*)alloc((size_t)NN*128*4);
  float* hnorm   = (float*)alloc((size_t)NN*128*4);
  float* pooled  = (float*)alloc(64*1024*4);
  float* fc1     = (float*)alloc(64*512*4);
  float* fc2     = (float*)alloc(64*256*4);
  float* fc3raw  = (float*)alloc(64*64*4);
  unsigned short* agg_bf = (unsigned short*)alloc((size_t)NN*128*2);
  unsigned short* wt_bf  = (unsigned short*)alloc(1024*128*2);
  unsigned* pmax = (unsigned*)alloc(64*1024*4);
  unsigned* pmin = (unsigned*)alloc(64*1024*4);

  const int RPB = CDIV(NN, 64);

  // graph prep
  k_prep<<<CDIV(NN,256),256,0,stream>>>(deg);
  k_deg<<<CDIV(EE,256),256,0,stream>>>(edst, deg);
  k_scan<<<1,1024,0,stream>>>(deg, offsets, cursor, dinv);
  k_fill<<<CDIV(EE+NN,256),256,0,stream>>>(esrc, edst, dinv, cursor, csr_src, csr_w);
  k_goff<<<CDIV(NN,256),256,0,stream>>>(batch, goff);

  // ---- layer 1 ----
  k_agg<6,8,32><<<CDIV(NN,32),dim3(8,32),0,stream>>>(x, offsets, csr_src, csr_w, agg);
  k_gemm_small<6,32,32><<<NN/32,256,0,stream>>>(agg, W1, b1, hbuf);
  hipMemsetAsync(stats, 0, 2*32*4, stream);
  k_stats<<<dim3(1,64),dim3(64,4),0,stream>>>(hbuf, stats, 32, RPB);
  k_finalize<<<1,64,0,stream>>>(stats, 32, 1.f/NN);
  k_bnrelu<<<CDIV(NN*32,256),256,0,stream>>>(hbuf, stats, g1, be1, hnorm, NN*32, 32);

  // ---- layer 2 ----
  k_agg<32,32,8><<<CDIV(NN,8),dim3(32,8),0,stream>>>(hnorm, offsets, csr_src, csr_w, agg);
  k_gemm_small<32,64,16><<<NN/16,256,0,stream>>>(agg, W2, b2, hbuf);
  hipMemsetAsync(stats, 0, 2*64*4, stream);
  k_stats<<<dim3(1,64),dim3(64,4),0,stream>>>(hbuf, stats, 64, RPB);
  k_finalize<<<1,64,0,stream>>>(stats, 64, 1.f/NN);
  k_bnrelu<<<CDIV(NN*64,256),256,0,stream>>>(hbuf, stats, g2, be2, hnorm, NN*64, 64);

  // ---- layer 3 ----
  k_agg<64,64,4><<<CDIV(NN,4),dim3(64,4),0,stream>>>(hnorm, offsets, csr_src, csr_w, agg);
  k_gemm_small<64,128,16><<<NN/16,256,0,stream>>>(agg, W3, b3, hbuf);
  hipMemsetAsync(stats, 0, 2*128*4, stream);
  k_stats<<<dim3(2,64),dim3(64,4),0,stream>>>(hbuf, stats, 128, RPB);
  k_finalize<<<1,128,0,stream>>>(stats, 128, 1.f/NN);
  k_bnrelu<<<CDIV(NN*128,256),256,0,stream>>>(hbuf, stats, g3, be3, hnorm, NN*128, 128);

  // ---- layer 4: bf16 MFMA + fused stats/pool ----
  k_agg_bf<<<CDIV(NN,2),dim3(128,2),0,stream>>>(hnorm, offsets, csr_src, csr_w, agg_bf);
  k_wprep<<<CDIV(128*1024,256),256,0,stream>>>(W4, wt_bf);
  hipMemsetAsync(stats, 0, 2*1024*4, stream);
  hipMemsetAsync(pmax, 0x00, 64*1024*4, stream);
  hipMemsetAsync(pmin, 0xFF, 64*1024*4, stream);
  k_gemm_l4_mfma<<<dim3(CDIV(NN,128),8),256,0,stream>>>(agg_bf, wt_bf, b4, batch, stats, pmax, pmin);
  k_finalize<<<4,256,0,stream>>>(stats, 1024, 1.f/NN);
  k_bnpool<<<CDIV(64*1024,256),256,0,stream>>>(pmax, pmin, stats, g4, be4, pooled);

  // ---- FC head ----
  k_bias_init<<<CDIV(64*512,256),256,0,stream>>>(fc1, b5, 512);
  k_fc_tile<1024,512,128><<<dim3(8,8),dim3(64,4),0,stream>>>(pooled, W5, fc1);
  k_bn_rows<<<8,dim3(64,8),0,stream>>>(fc1, g5, be5, 512);

  k_bias_init<<<CDIV(64*256,256),256,0,stream>>>(fc2, b6, 256);
  k_fc_tile<512,256,128><<<dim3(4,4),dim3(64,4),0,stream>>>(fc1, W6, fc2);
  k_bn_rows<<<4,dim3(64,8),0,stream>>>(fc2, g6, be6, 256);

  k_bias_init<<<CDIV(64*64,256),256,0,stream>>>(fc3raw, b7, 64);
  k_fc_tile<256,64,64><<<dim3(1,4),dim3(64,4),0,stream>>>(fc2, W7, fc3raw);
  k_l2norm<<<64,64,0,stream>>>(fc3raw, (float*)d_out);
}

// Round 6
// 508.858 us; speedup vs baseline: 2.3688x; 1.1196x over previous
//
#include <hip/hip_runtime.h>
#include <math.h>

#define NN 20000
#define EE 256000
#define GG 64
#define CDIV(a,b) (((a)+(b)-1)/(b))

typedef __attribute__((ext_vector_type(8))) short bf16x8;
typedef __attribute__((ext_vector_type(4))) float f32x4;

__device__ __forceinline__ unsigned fkey(float f) {
  unsigned u = __float_as_uint(f);
  return (u & 0x80000000u) ? ~u : (u | 0x80000000u);
}
__device__ __forceinline__ float fdec(unsigned k) {
  unsigned u = (k & 0x80000000u) ? (k ^ 0x80000000u) : ~k;
  return __uint_as_float(u);
}
__device__ __forceinline__ unsigned short rne_bf16(float f) {
  unsigned u = __float_as_uint(f);
  unsigned r = (u + 0x7fffu + ((u >> 16) & 1u)) >> 16;
  return (unsigned short)r;
}

// ---------------- graph preprocessing ----------------

__global__ void k_prep(int* deg) {
  int i = blockIdx.x*blockDim.x + threadIdx.x;
  if (i < NN) deg[i] = 1;   // self-loop
}

__global__ void k_deg(const int* __restrict__ dst, int* deg) {
  int i = blockIdx.x*blockDim.x + threadIdx.x;
  if (i < EE) atomicAdd(&deg[dst[i]], 1);
}

__global__ void k_scan(const int* __restrict__ deg, int* __restrict__ offsets,
                       int* __restrict__ cursor, float* __restrict__ dinv) {
  __shared__ int sums[1024];
  const int PER = 20;
  int t = threadIdx.x;
  int base = t * PER;
  int local[PER];
  int s = 0;
  #pragma unroll
  for (int i = 0; i < PER; ++i) {
    int idx = base + i;
    int d = (idx < NN) ? deg[idx] : 0;
    local[i] = s;
    s += d;
  }
  sums[t] = s;
  __syncthreads();
  for (int off = 1; off < 1024; off <<= 1) {
    int v = (t >= off) ? sums[t - off] : 0;
    __syncthreads();
    sums[t] += v;
    __syncthreads();
  }
  int block_excl = (t == 0) ? 0 : sums[t - 1];
  #pragma unroll
  for (int i = 0; i < PER; ++i) {
    int idx = base + i;
    if (idx < NN) {
      int off = block_excl + local[i];
      offsets[idx] = off;
      cursor[idx]  = off;
      dinv[idx] = rsqrtf((float)deg[idx]);
    }
  }
  if (t == 1023) offsets[NN] = sums[1023];
}

__global__ void k_fill(const int* __restrict__ srcv, const int* __restrict__ dstv,
                       const float* __restrict__ dinv, int* cursor,
                       int* __restrict__ csr_src, float* __restrict__ csr_w) {
  int i = blockIdx.x*blockDim.x + threadIdx.x;
  if (i < EE) {
    int s = srcv[i], d = dstv[i];
    int pos = atomicAdd(&cursor[d], 1);
    csr_src[pos] = s;
    csr_w[pos] = dinv[s] * dinv[d];
  } else if (i < EE + NN) {
    int n = i - EE;
    int pos = atomicAdd(&cursor[n], 1);
    csr_src[pos] = n;
    float di = dinv[n];
    csr_w[pos] = di * di;
  }
}

__global__ void k_goff(const int* __restrict__ batch, int* __restrict__ goff) {
  int i = blockIdx.x*blockDim.x + threadIdx.x;
  if (i >= NN) return;
  int b = batch[i];
  int bp = (i == 0) ? -1 : batch[i-1];
  for (int g = bp + 1; g <= b; ++g) goff[g] = i;
  if (i == NN-1) for (int g = b+1; g <= GG; ++g) goff[g] = NN;
}

// ---------------- aggregation ----------------

template<int C, int TX, int TY>
__global__ void k_agg(const float* __restrict__ in, const int* __restrict__ offsets,
                      const int* __restrict__ csr_src, const float* __restrict__ csr_w,
                      float* __restrict__ out) {
  int node = blockIdx.x * TY + threadIdx.y;
  if (node >= NN) return;
  int x = threadIdx.x;
  int k0 = offsets[node], k1 = offsets[node+1];
  if (x < C) {
    float acc = 0.f;
    for (int k = k0; k < k1; ++k) {
      int s = csr_src[k];
      float w = csr_w[k];
      acc += w * in[s*C + x];
    }
    out[node*C + x] = acc;
  }
}

// layer-4 aggregation, emits bf16 directly
__global__ void k_agg_bf(const float* __restrict__ in, const int* __restrict__ offsets,
                         const int* __restrict__ csr_src, const float* __restrict__ csr_w,
                         unsigned short* __restrict__ out) {
  int node = blockIdx.x * 2 + threadIdx.y;
  if (node >= NN) return;
  int x = threadIdx.x;  // 0..127
  int k0 = offsets[node], k1 = offsets[node+1];
  float acc = 0.f;
  for (int k = k0; k < k1; ++k) {
    int s = csr_src[k];
    float w = csr_w[k];
    acc += w * in[s*128 + x];
  }
  out[node*128 + x] = rne_bf16(acc);
}

// W4 [128,1024] fp32 -> Wt [1024,128] bf16
__global__ void k_wprep(const float* __restrict__ W, unsigned short* __restrict__ out) {
  int i = blockIdx.x*256 + threadIdx.x;
  if (i >= 128*1024) return;
  int k = i >> 10, c = i & 1023;
  out[c*128 + k] = rne_bf16(W[i]);
}

// ---------------- small GEMM (layers 1-3) ----------------

template<int K, int OUT, int ROWS>
__global__ __launch_bounds__(256) void k_gemm_small(
    const float* __restrict__ A, const float* __restrict__ W,
    const float* __restrict__ b, float* __restrict__ out) {
  __shared__ float Ws[K*OUT];
  __shared__ float As[ROWS*K];
  int t = threadIdx.x;
  for (int i = t; i < K*OUT; i += 256) Ws[i] = W[i];
  int row0 = blockIdx.x * ROWS;
  for (int i = t; i < ROWS*K; i += 256) As[i] = A[row0*K + i];
  __syncthreads();
  const int RG  = 256 / OUT;
  const int RPT = ROWS / RG;
  int j  = t % OUT;
  int rg = t / OUT;
  float bias = b[j];
  float acc[RPT];
  #pragma unroll
  for (int i = 0; i < RPT; ++i) acc[i] = bias;
  for (int k = 0; k < K; ++k) {
    float w = Ws[k*OUT + j];
    #pragma unroll
    for (int i = 0; i < RPT; ++i)
      acc[i] += As[(rg*RPT + i)*K + k] * w;
  }
  #pragma unroll
  for (int i = 0; i < RPT; ++i)
    out[(row0 + rg*RPT + i)*OUT + j] = acc[i];
}

// ---------------- layer-4: bf16 MFMA GEMM with fused stats+pool epilogue ----------------

__global__ __launch_bounds__(256) void k_gemm_l4_mfma(
    const unsigned short* __restrict__ A, const unsigned short* __restrict__ Bt,
    const float* __restrict__ bias, const int* __restrict__ batch,
    float* __restrict__ stats, unsigned* __restrict__ pmax, unsigned* __restrict__ pmin) {
  __shared__ unsigned short As[128*128];
  __shared__ unsigned short Bs[128*128];
  int t = threadIdx.x;
  int row0 = blockIdx.x * 128;
  int col0 = blockIdx.y * 128;
  #pragma unroll
  for (int j = 0; j < 8; ++j) {
    int c = j*256 + t;
    int r = c >> 4, ck = c & 15;
    int rg = row0 + r;
    ulonglong2 v; v.x = 0; v.y = 0;
    if (rg < NN) v = *(const ulonglong2*)&A[rg*128 + ck*8];
    *(ulonglong2*)&As[r*128 + (ck ^ (r & 7))*8] = v;
  }
  #pragma unroll
  for (int j = 0; j < 8; ++j) {
    int c = j*256 + t;
    int r = c >> 4, ck = c & 15;
    ulonglong2 v = *(const ulonglong2*)&Bt[(col0 + r)*128 + ck*8];
    *(ulonglong2*)&Bs[r*128 + (ck ^ (r & 7))*8] = v;
  }
  __syncthreads();

  int w = t >> 6, l = t & 63;
  int wr = w >> 1, wc = w & 1;
  int lrow = l & 15, lk = l >> 4;
  f32x4 acc[4][4] = {};
  #pragma unroll
  for (int ks = 0; ks < 4; ++ks) {
    int kc = ks*4 + lk;
    bf16x8 a[4], b[4];
    #pragma unroll
    for (int m = 0; m < 4; ++m) {
      int r = wr*64 + m*16 + lrow;
      a[m] = *(const bf16x8*)&As[r*128 + (kc ^ (r & 7))*8];
    }
    #pragma unroll
    for (int n = 0; n < 4; ++n) {
      int r = wc*64 + n*16 + lrow;
      b[n] = *(const bf16x8*)&Bs[r*128 + (kc ^ (r & 7))*8];
    }
    #pragma unroll
    for (int m = 0; m < 4; ++m)
      #pragma unroll
      for (int n = 0; n < 4; ++n)
        acc[m][n] = __builtin_amdgcn_mfma_f32_16x16x32_bf16(a[m], b[n], acc[m][n], 0, 0, 0);
  }

  // ---- epilogue ----
  int rbase = row0 + wr*64;
  float bias_n[4];
  #pragma unroll
  for (int n = 0; n < 4; ++n) bias_n[n] = bias[col0 + wc*64 + n*16 + lrow];

  float s[4] = {}, ss[4] = {};
  float mx[4], mn[4];
  #pragma unroll
  for (int n = 0; n < 4; ++n) { mx[n] = -3.4e38f; mn[n] = 3.4e38f; }
  #pragma unroll
  for (int m = 0; m < 4; ++m)
    #pragma unroll
    for (int r = 0; r < 4; ++r) {
      int row_g = rbase + m*16 + lk*4 + r;
      if (row_g < NN) {
        #pragma unroll
        for (int n = 0; n < 4; ++n) {
          float v = acc[m][n][r] + bias_n[n];
          s[n] += v; ss[n] += v*v;
          mx[n] = fmaxf(mx[n], v); mn[n] = fminf(mn[n], v);
        }
      }
    }
  #pragma unroll
  for (int n = 0; n < 4; ++n) {
    s[n]  += __shfl_xor(s[n], 16);  s[n]  += __shfl_xor(s[n], 32);
    ss[n] += __shfl_xor(ss[n], 16); ss[n] += __shfl_xor(ss[n], 32);
  }
  if (l < 16) {
    #pragma unroll
    for (int n = 0; n < 4; ++n) {
      int cg = col0 + wc*64 + n*16 + l;
      atomicAdd(&stats[cg], s[n]);
      atomicAdd(&stats[1024 + cg], ss[n]);
    }
  }
  // pool: per-graph raw max/min
  if (rbase < NN) {
    int rlast = min(rbase + 63, NN - 1);
    int glo = batch[rbase], ghi = batch[rlast];
    if (glo == ghi) {
      #pragma unroll
      for (int n = 0; n < 4; ++n) {
        mx[n] = fmaxf(mx[n], __shfl_xor(mx[n], 16)); mx[n] = fmaxf(mx[n], __shfl_xor(mx[n], 32));
        mn[n] = fminf(mn[n], __shfl_xor(mn[n], 16)); mn[n] = fminf(mn[n], __shfl_xor(mn[n], 32));
      }
      if (l < 16) {
        #pragma unroll
        for (int n = 0; n < 4; ++n) {
          int cg = col0 + wc*64 + n*16 + l;
          atomicMax(&pmax[glo*1024 + cg], fkey(mx[n]));
          atomicMin(&pmin[glo*1024 + cg], fkey(mn[n]));
        }
      }
    } else {
      // graph boundary inside span: masked per-graph wave reduction
      // (replaces per-value global atomics: 128 atomics/graph/wave, not 8192/wave)
      int gb[4][4];
      #pragma unroll
      for (int m = 0; m < 4; ++m)
        #pragma unroll
        for (int r = 0; r < 4; ++r) {
          int row_g = rbase + m*16 + lk*4 + r;
          gb[m][r] = (row_g < NN) ? batch[row_g] : -1;
        }
      for (int g = glo; g <= ghi; ++g) {
        float gmx[4], gmn[4];
        #pragma unroll
        for (int n = 0; n < 4; ++n) { gmx[n] = -3.4e38f; gmn[n] = 3.4e38f; }
        #pragma unroll
        for (int m = 0; m < 4; ++m)
          #pragma unroll
          for (int r = 0; r < 4; ++r) {
            bool in_g = (gb[m][r] == g);
            #pragma unroll
            for (int n = 0; n < 4; ++n) {
              float v = acc[m][n][r] + bias_n[n];
              gmx[n] = in_g ? fmaxf(gmx[n], v) : gmx[n];
              gmn[n] = in_g ? fminf(gmn[n], v) : gmn[n];
            }
          }
        #pragma unroll
        for (int n = 0; n < 4; ++n) {
          gmx[n] = fmaxf(gmx[n], __shfl_xor(gmx[n], 16)); gmx[n] = fmaxf(gmx[n], __shfl_xor(gmx[n], 32));
          gmn[n] = fminf(gmn[n], __shfl_xor(gmn[n], 16)); gmn[n] = fminf(gmn[n], __shfl_xor(gmn[n], 32));
        }
        if (l < 16) {
          #pragma unroll
          for (int n = 0; n < 4; ++n) {
            int cg = col0 + wc*64 + n*16 + l;
            if (gmx[n] > -3.0e38f) atomicMax(&pmax[g*1024 + cg], fkey(gmx[n]));
            if (gmn[n] <  3.0e38f) atomicMin(&pmin[g*1024 + cg], fkey(gmn[n]));
          }
        }
      }
    }
  }
}

// ---------------- batchnorm pieces (layers 1-3) ----------------

__global__ void k_stats(const float* __restrict__ h, float* __restrict__ stats,
                        int C, int rows_per_block) {
  int c = blockIdx.x*64 + threadIdx.x;
  int r0 = blockIdx.y * rows_per_block;
  int r1 = min(NN, r0 + rows_per_block);
  float s = 0.f, ss = 0.f;
  if (c < C) {
    for (int r = r0 + threadIdx.y; r < r1; r += 4) {
      float v = h[r*C + c];
      s += v; ss += v*v;
    }
  }
  __shared__ float red[2][4][64];
  red[0][threadIdx.y][threadIdx.x] = s;
  red[1][threadIdx.y][threadIdx.x] = ss;
  __syncthreads();
  if (threadIdx.y == 0 && c < C) {
    s  = red[0][0][threadIdx.x]+red[0][1][threadIdx.x]+red[0][2][threadIdx.x]+red[0][3][threadIdx.x];
    ss = red[1][0][threadIdx.x]+red[1][1][threadIdx.x]+red[1][2][threadIdx.x]+red[1][3][threadIdx.x];
    atomicAdd(&stats[c], s);
    atomicAdd(&stats[C+c], ss);
  }
}

__global__ void k_finalize(float* stats, int C, float invN) {
  int c = blockIdx.x*blockDim.x + threadIdx.x;
  if (c < C) {
    float m = stats[c] * invN;
    float v = stats[C+c]*invN - m*m;
    stats[c] = m;
    stats[C+c] = rsqrtf(v + 1e-5f);
  }
}

__global__ void k_bnrelu(const float* __restrict__ h, const float* __restrict__ stats,
                         const float* __restrict__ g, const float* __restrict__ be,
                         float* __restrict__ out, int total, int C) {
  int i = blockIdx.x*blockDim.x + threadIdx.x;
  if (i >= total) return;
  int c = i % C;
  float m = stats[c], rstd = stats[C+c];
  float v = (h[i]-m)*rstd*g[c] + be[c];
  out[i] = fmaxf(v, 0.f);
}

// apply BN+relu to pooled raw max/min [64,1024]
__global__ void k_bnpool(const unsigned* __restrict__ pmax, const unsigned* __restrict__ pmin,
                         const float* __restrict__ stats, const float* __restrict__ g,
                         const float* __restrict__ be, float* __restrict__ p) {
  int i = blockIdx.x*256 + threadIdx.x;
  if (i >= 64*1024) return;
  int c = i & 1023;
  float mean = stats[c], rstd = stats[1024+c];
  float sc = g[c]*rstd, sh = be[c] - mean*sc;
  float v = (sc >= 0.f) ? fdec(pmax[i]) : fdec(pmin[i]);
  p[i] = fmaxf(v*sc + sh, 0.f);
}

// ---------------- FC head: K-split LDS-tiled GEMM + atomics ----------------

__global__ void k_bias_init(float* __restrict__ out, const float* __restrict__ b, int OUT) {
  int i = blockIdx.x*blockDim.x + threadIdx.x;
  if (i < 64*OUT) out[i] = b[i % OUT];
}

template<int K, int OUT, int KT>
__global__ __launch_bounds__(256) void k_fc_tile(
    const float* __restrict__ A, const float* __restrict__ W,
    float* __restrict__ out) {
  __shared__ float As[64][KT];
  __shared__ float Ws[KT][64];
  int t = threadIdx.y*64 + threadIdx.x;
  int j0 = blockIdx.x*64;
  int k0 = blockIdx.y*KT;
  #pragma unroll 4
  for (int i = t; i < 64*KT/4; i += 256) {
    int r  = i / (KT/4);
    int c4 = i % (KT/4);
    float4 v = *(const float4*)&A[r*K + k0 + c4*4];
    *(float4*)&As[r][c4*4] = v;
  }
  #pragma unroll 4
  for (int i = t; i < KT*16; i += 256) {
    int k  = i / 16;
    int c4 = i % 16;
    float4 v = *(const float4*)&W[(k0+k)*OUT + j0 + c4*4];
    *(float4*)&Ws[k][c4*4] = v;
  }
  __syncthreads();
  int j  = threadIdx.x;
  int r0 = threadIdx.y*16;
  float acc[16] = {};
  for (int kk = 0; kk < KT; ++kk) {
    float w = Ws[kk][j];
    #pragma unroll
    for (int i = 0; i < 16; ++i) acc[i] += As[r0+i][kk] * w;
  }
  #pragma unroll
  for (int i = 0; i < 16; ++i) atomicAdd(&out[(r0+i)*OUT + j0 + j], acc[i]);
}

__global__ __launch_bounds__(512) void k_bn_rows(
    float* __restrict__ h, const float* __restrict__ g,
    const float* __restrict__ be, int C) {
  int c = blockIdx.x*64 + threadIdx.x;
  int y = threadIdx.y;
  float v[8];
  float s = 0.f, ss = 0.f;
  #pragma unroll
  for (int i = 0; i < 8; ++i) {
    v[i] = h[(y*8+i)*C + c];
    s += v[i]; ss += v[i]*v[i];
  }
  __shared__ float rs[8][64], rss[8][64], bc[2][64];
  rs[y][threadIdx.x] = s; rss[y][threadIdx.x] = ss;
  __syncthreads();
  if (y == 0) {
    s = 0.f; ss = 0.f;
    #pragma unroll
    for (int i = 0; i < 8; ++i) { s += rs[i][threadIdx.x]; ss += rss[i][threadIdx.x]; }
    float m = s*(1.f/64.f);
    float var = ss*(1.f/64.f) - m*m;
    float rstd = rsqrtf(var + 1e-5f);
    float sc = g[c]*rstd;
    bc[0][threadIdx.x] = sc;
    bc[1][threadIdx.x] = be[c] - m*sc;
  }
  __syncthreads();
  float sc = bc[0][threadIdx.x], sh = bc[1][threadIdx.x];
  #pragma unroll
  for (int i = 0; i < 8; ++i)
    h[(y*8+i)*C + c] = fmaxf(v[i]*sc + sh, 0.f);
}

__global__ void k_l2norm(const float* __restrict__ in, float* __restrict__ out) {
  int r = blockIdx.x, j = threadIdx.x;
  float v = in[r*64 + j];
  float ss = v*v;
  #pragma unroll
  for (int off = 1; off < 64; off <<= 1) ss += __shfl_xor(ss, off);
  float inv = 1.f / fmaxf(sqrtf(ss), 1e-12f);
  out[r*64 + j] = v * inv;
}

// ---------------- launch ----------------

extern "C" void kernel_launch(void* const* d_in, const int* in_sizes, int n_in,
                              void* d_out, int out_size, void* d_ws, size_t ws_size,
                              hipStream_t stream) {
  const float* x    = (const float*)d_in[0];
  const int*   ei   = (const int*)d_in[1];
  const int*   batch= (const int*)d_in[2];
  const float* W1=(const float*)d_in[3],  *b1=(const float*)d_in[4],  *g1=(const float*)d_in[5],  *be1=(const float*)d_in[6];
  const float* W2=(const float*)d_in[7],  *b2=(const float*)d_in[8],  *g2=(const float*)d_in[9],  *be2=(const float*)d_in[10];
  const float* W3=(const float*)d_in[11], *b3=(const float*)d_in[12], *g3=(const float*)d_in[13], *be3=(const float*)d_in[14];
  const float* W4=(const float*)d_in[15], *b4=(const float*)d_in[16], *g4=(const float*)d_in[17], *be4=(const float*)d_in[18];
  const float* W5=(const float*)d_in[19], *b5=(const float*)d_in[20], *g5=(const float*)d_in[21], *be5=(const float*)d_in[22];
  const float* W6=(const float*)d_in[23], *b6=(const float*)d_in[24], *g6=(const float*)d_in[25], *be6=(const float*)d_in[26];
  const float* W7=(const float*)d_in[27], *b7=(const float*)d_in[28];
  const int* esrc = ei;
  const int* edst = ei + EE;

  char* w = (char*)d_ws;
  auto alloc = [&](size_t bytes) -> void* {
    void* p = (void*)w;
    w += (bytes + 255) & ~(size_t)255;
    return p;
  };
  int*   deg     = (int*)  alloc(NN*4);
  int*   offsets = (int*)  alloc((NN+1)*4);
  int*   cursor  = (int*)  alloc(NN*4);
  int*   goff    = (int*)  alloc((GG+1)*4);
  float* dinv    = (float*)alloc(NN*4);
  int*   csr_src = (int*)  alloc((EE+NN)*4);
  float* csr_w   = (float*)alloc((EE+NN)*4);
  float* stats   = (float*)alloc(2*1024*4);
  float* agg     = (float*)alloc((size_t)NN*128*4);
  float* hbuf    = (float*)alloc((size_t)NN*128*4);
  float* hnorm   = (float*)alloc((size_t)NN*128*4);
  float* pooled  = (float*)alloc(64*1024*4);
  float* fc1     = (float*)alloc(64*512*4);
  float* fc2     = (float*)alloc(64*256*4);
  float* fc3raw  = (float*)alloc(64*64*4);
  unsigned short* agg_bf = (unsigned short*)alloc((size_t)NN*128*2);
  unsigned short* wt_bf  = (unsigned short*)alloc(1024*128*2);
  unsigned* pmax = (unsigned*)alloc(64*1024*4);
  unsigned* pmin = (unsigned*)alloc(64*1024*4);

  const int RPB = CDIV(NN, 64);

  // graph prep
  k_prep<<<CDIV(NN,256),256,0,stream>>>(deg);
  k_deg<<<CDIV(EE,256),256,0,stream>>>(edst, deg);
  k_scan<<<1,1024,0,stream>>>(deg, offsets, cursor, dinv);
  k_fill<<<CDIV(EE+NN,256),256,0,stream>>>(esrc, edst, dinv, cursor, csr_src, csr_w);
  k_goff<<<CDIV(NN,256),256,0,stream>>>(batch, goff);

  // ---- layer 1 ----
  k_agg<6,8,32><<<CDIV(NN,32),dim3(8,32),0,stream>>>(x, offsets, csr_src, csr_w, agg);
  k_gemm_small<6,32,32><<<NN/32,256,0,stream>>>(agg, W1, b1, hbuf);
  hipMemsetAsync(stats, 0, 2*32*4, stream);
  k_stats<<<dim3(1,64),dim3(64,4),0,stream>>>(hbuf, stats, 32, RPB);
  k_finalize<<<1,64,0,stream>>>(stats, 32, 1.f/NN);
  k_bnrelu<<<CDIV(NN*32,256),256,0,stream>>>(hbuf, stats, g1, be1, hnorm, NN*32, 32);

  // ---- layer 2 ----
  k_agg<32,32,8><<<CDIV(NN,8),dim3(32,8),0,stream>>>(hnorm, offsets, csr_src, csr_w, agg);
  k_gemm_small<32,64,16><<<NN/16,256,0,stream>>>(agg, W2, b2, hbuf);
  hipMemsetAsync(stats, 0, 2*64*4, stream);
  k_stats<<<dim3(1,64),dim3(64,4),0,stream>>>(hbuf, stats, 64, RPB);
  k_finalize<<<1,64,0,stream>>>(stats, 64, 1.f/NN);
  k_bnrelu<<<CDIV(NN*64,256),256,0,stream>>>(hbuf, stats, g2, be2, hnorm, NN*64, 64);

  // ---- layer 3 ----
  k_agg<64,64,4><<<CDIV(NN,4),dim3(64,4),0,stream>>>(hnorm, offsets, csr_src, csr_w, agg);
  k_gemm_small<64,128,16><<<NN/16,256,0,stream>>>(agg, W3, b3, hbuf);
  hipMemsetAsync(stats, 0, 2*128*4, stream);
  k_stats<<<dim3(2,64),dim3(64,4),0,stream>>>(hbuf, stats, 128, RPB);
  k_finalize<<<1,128,0,stream>>>(stats, 128, 1.f/NN);
  k_bnrelu<<<CDIV(NN*128,256),256,0,stream>>>(hbuf, stats, g3, be3, hnorm, NN*128, 128);

  // ---- layer 4: bf16 MFMA + fused stats/pool ----
  k_agg_bf<<<CDIV(NN,2),dim3(128,2),0,stream>>>(hnorm, offsets, csr_src, csr_w, agg_bf);
  k_wprep<<<CDIV(128*1024,256),256,0,stream>>>(W4, wt_bf);
  hipMemsetAsync(stats, 0, 2*1024*4, stream);
  hipMemsetAsync(pmax, 0x00, 64*1024*4, stream);
  hipMemsetAsync(pmin, 0xFF, 64*1024*4, stream);
  k_gemm_l4_mfma<<<dim3(CDIV(NN,128),8),256,0,stream>>>(agg_bf, wt_bf, b4, batch, stats, pmax, pmin);
  k_finalize<<<4,256,0,stream>>>(stats, 1024, 1.f/NN);
  k_bnpool<<<CDIV(64*1024,256),256,0,stream>>>(pmax, pmin, stats, g4, be4, pooled);

  // ---- FC head ----
  k_bias_init<<<CDIV(64*512,256),256,0,stream>>>(fc1, b5, 512);
  k_fc_tile<1024,512,128><<<dim3(8,8),dim3(64,4),0,stream>>>(pooled, W5, fc1);
  k_bn_rows<<<8,dim3(64,8),0,stream>>>(fc1, g5, be5, 512);

  k_bias_init<<<CDIV(64*256,256),256,0,stream>>>(fc2, b6, 256);
  k_fc_tile<512,256,128><<<dim3(4,4),dim3(64,4),0,stream>>>(fc1, W6, fc2);
  k_bn_rows<<<4,dim3(64,8),0,stream>>>(fc2, g6, be6, 256);

  k_bias_init<<<CDIV(64*64,256),256,0,stream>>>(fc3raw, b7, 64);
  k_fc_tile<256,64,64><<<dim3(1,4),dim3(64,4),0,stream>>>(fc2, W7, fc3raw);
  k_l2norm<<<64,64,0,stream>>>(fc3raw, (float*)d_out);
}

// Round 7
// 393.746 us; speedup vs baseline: 3.0614x; 1.2924x over previous
//
#include <hip/hip_runtime.h>
#include <math.h>

#define NN 20000
#define EE 256000
#define GG 64
#define CDIV(a,b) (((a)+(b)-1)/(b))

typedef __attribute__((ext_vector_type(8))) short bf16x8;
typedef __attribute__((ext_vector_type(4))) float f32x4;

__device__ __forceinline__ unsigned fkey(float f) {
  unsigned u = __float_as_uint(f);
  return (u & 0x80000000u) ? ~u : (u | 0x80000000u);
}
__device__ __forceinline__ float fdec(unsigned k) {
  unsigned u = (k & 0x80000000u) ? (k ^ 0x80000000u) : ~k;
  return __uint_as_float(u);
}
__device__ __forceinline__ unsigned short rne_bf16(float f) {
  unsigned u = __float_as_uint(f);
  unsigned r = (u + 0x7fffu + ((u >> 16) & 1u)) >> 16;
  return (unsigned short)r;
}

// ---------------- graph preprocessing ----------------

__global__ void k_prep(int* deg) {
  int i = blockIdx.x*blockDim.x + threadIdx.x;
  if (i < NN) deg[i] = 1;   // self-loop
}

__global__ void k_deg(const int* __restrict__ dst, int* deg) {
  int i = blockIdx.x*blockDim.x + threadIdx.x;
  if (i < EE) atomicAdd(&deg[dst[i]], 1);
}

__global__ void k_scan(const int* __restrict__ deg, int* __restrict__ offsets,
                       int* __restrict__ cursor, float* __restrict__ dinv) {
  __shared__ int sums[1024];
  const int PER = 20;
  int t = threadIdx.x;
  int base = t * PER;
  int local[PER];
  int s = 0;
  #pragma unroll
  for (int i = 0; i < PER; ++i) {
    int idx = base + i;
    int d = (idx < NN) ? deg[idx] : 0;
    local[i] = s;
    s += d;
  }
  sums[t] = s;
  __syncthreads();
  for (int off = 1; off < 1024; off <<= 1) {
    int v = (t >= off) ? sums[t - off] : 0;
    __syncthreads();
    sums[t] += v;
    __syncthreads();
  }
  int block_excl = (t == 0) ? 0 : sums[t - 1];
  #pragma unroll
  for (int i = 0; i < PER; ++i) {
    int idx = base + i;
    if (idx < NN) {
      int off = block_excl + local[i];
      offsets[idx] = off;
      cursor[idx]  = off;
      dinv[idx] = rsqrtf((float)deg[idx]);
    }
  }
  if (t == 1023) offsets[NN] = sums[1023];
}

__global__ void k_fill(const int* __restrict__ srcv, const int* __restrict__ dstv,
                       const float* __restrict__ dinv, int* cursor,
                       int* __restrict__ csr_src, float* __restrict__ csr_w) {
  int i = blockIdx.x*blockDim.x + threadIdx.x;
  if (i < EE) {
    int s = srcv[i], d = dstv[i];
    int pos = atomicAdd(&cursor[d], 1);
    csr_src[pos] = s;
    csr_w[pos] = dinv[s] * dinv[d];
  } else if (i < EE + NN) {
    int n = i - EE;
    int pos = atomicAdd(&cursor[n], 1);
    csr_src[pos] = n;
    float di = dinv[n];
    csr_w[pos] = di * di;
  }
}

// ---------------- aggregation ----------------

// layer-1: raw x input [N,6]
template<int C, int TX, int TY>
__global__ void k_agg(const float* __restrict__ in, const int* __restrict__ offsets,
                      const int* __restrict__ csr_src, const float* __restrict__ csr_w,
                      float* __restrict__ out) {
  int node = blockIdx.x * TY + threadIdx.y;
  if (node >= NN) return;
  int x = threadIdx.x;
  int k0 = offsets[node], k1 = offsets[node+1];
  if (x < C) {
    float acc = 0.f;
    for (int k = k0; k < k1; ++k) {
      int s = csr_src[k];
      float w = csr_w[k];
      acc += w * in[s*C + x];
    }
    out[node*C + x] = acc;
  }
}

// layers 2-3: gather with BN+ReLU fused on the fly, float4 lanes
template<int C, int TY>
__global__ void k_agg_f4(const float* __restrict__ in, const float* __restrict__ st,
                         const float* __restrict__ g, const float* __restrict__ be,
                         const int* __restrict__ offsets, const int* __restrict__ csr_src,
                         const float* __restrict__ csr_w, float* __restrict__ out) {
  int node = blockIdx.x*TY + threadIdx.y;
  if (node >= NN) return;
  int c0 = threadIdx.x*4;
  float4 mean = *(const float4*)&st[c0];
  float4 rstd = *(const float4*)&st[C+c0];
  float4 gv = *(const float4*)&g[c0];
  float4 bv = *(const float4*)&be[c0];
  float sx = gv.x*rstd.x, hx = bv.x - mean.x*sx;
  float sy = gv.y*rstd.y, hy = bv.y - mean.y*sy;
  float sz = gv.z*rstd.z, hz = bv.z - mean.z*sz;
  float sw = gv.w*rstd.w, hw = bv.w - mean.w*sw;
  int k0 = offsets[node], k1 = offsets[node+1];
  float a0=0.f,a1=0.f,a2=0.f,a3=0.f;
  for (int k = k0; k < k1; ++k) {
    int s = csr_src[k]; float w = csr_w[k];
    float4 v = *(const float4*)&in[s*C + c0];
    a0 += w*fmaxf(v.x*sx+hx, 0.f);
    a1 += w*fmaxf(v.y*sy+hy, 0.f);
    a2 += w*fmaxf(v.z*sz+hz, 0.f);
    a3 += w*fmaxf(v.w*sw+hw, 0.f);
  }
  *(float4*)&out[node*C+c0] = make_float4(a0,a1,a2,a3);
}

// layer-4: gather [N,128] with BN+ReLU fused, emits bf16
__global__ void k_agg_bf_f4(const float* __restrict__ in, const float* __restrict__ st,
                            const float* __restrict__ g, const float* __restrict__ be,
                            const int* __restrict__ offsets, const int* __restrict__ csr_src,
                            const float* __restrict__ csr_w, unsigned short* __restrict__ out) {
  int node = blockIdx.x*8 + threadIdx.y;   // block (32,8)
  if (node >= NN) return;
  int c0 = threadIdx.x*4;
  float4 mean = *(const float4*)&st[c0];
  float4 rstd = *(const float4*)&st[128+c0];
  float4 gv = *(const float4*)&g[c0];
  float4 bv = *(const float4*)&be[c0];
  float sx = gv.x*rstd.x, hx = bv.x - mean.x*sx;
  float sy = gv.y*rstd.y, hy = bv.y - mean.y*sy;
  float sz = gv.z*rstd.z, hz = bv.z - mean.z*sz;
  float sw = gv.w*rstd.w, hw = bv.w - mean.w*sw;
  int k0 = offsets[node], k1 = offsets[node+1];
  float a0=0.f,a1=0.f,a2=0.f,a3=0.f;
  for (int k = k0; k < k1; ++k) {
    int s = csr_src[k]; float w = csr_w[k];
    float4 v = *(const float4*)&in[s*128 + c0];
    a0 += w*fmaxf(v.x*sx+hx, 0.f);
    a1 += w*fmaxf(v.y*sy+hy, 0.f);
    a2 += w*fmaxf(v.z*sz+hz, 0.f);
    a3 += w*fmaxf(v.w*sw+hw, 0.f);
  }
  ushort4 o;
  o.x = rne_bf16(a0); o.y = rne_bf16(a1); o.z = rne_bf16(a2); o.w = rne_bf16(a3);
  *(ushort4*)&out[node*128 + c0] = o;
}

// W4 [128,1024] fp32 -> Wt [1024,128] bf16
__global__ void k_wprep(const float* __restrict__ W, unsigned short* __restrict__ out) {
  int i = blockIdx.x*256 + threadIdx.x;
  if (i >= 128*1024) return;
  int k = i >> 10, c = i & 1023;
  out[c*128 + k] = rne_bf16(W[i]);
}

// ---------------- small GEMM (layers 1-3), no bias (cancels in BN), fused stats ----------------

template<int K, int OUT, int ROWS>
__global__ __launch_bounds__(256) void k_gemm_small(
    const float* __restrict__ A, const float* __restrict__ W,
    float* __restrict__ out, float* __restrict__ pstats) {
  constexpr int RG  = 256 / OUT;
  constexpr int RPT = ROWS / RG;
  __shared__ float Ws[K*OUT];
  __shared__ float As[ROWS*K];
  __shared__ float reds[2][RG][OUT];
  int t = threadIdx.x;
  for (int i = t; i < K*OUT; i += 256) Ws[i] = W[i];
  int row0 = blockIdx.x * ROWS;
  for (int i = t; i < ROWS*K; i += 256) As[i] = A[row0*K + i];
  __syncthreads();
  int j  = t % OUT;
  int rg = t / OUT;
  float acc[RPT] = {};
  for (int k = 0; k < K; ++k) {
    float w = Ws[k*OUT + j];
    #pragma unroll
    for (int i = 0; i < RPT; ++i)
      acc[i] += As[(rg*RPT + i)*K + k] * w;
  }
  float s = 0.f, ss = 0.f;
  #pragma unroll
  for (int i = 0; i < RPT; ++i) {
    out[(row0 + rg*RPT + i)*OUT + j] = acc[i];
    s += acc[i]; ss += acc[i]*acc[i];
  }
  reds[0][rg][j] = s; reds[1][rg][j] = ss;
  __syncthreads();
  if (rg == 0) {
    float S = 0.f, SS = 0.f;
    #pragma unroll
    for (int r = 0; r < RG; ++r) { S += reds[0][r][j]; SS += reds[1][r][j]; }
    int p = blockIdx.x & 15;
    atomicAdd(&pstats[p*2*OUT + j], S);
    atomicAdd(&pstats[p*2*OUT + OUT + j], SS);
  }
}

template<int C>
__global__ void k_finalize_ps(const float* __restrict__ pstats, float* __restrict__ stats) {
  int c = blockIdx.x*64 + threadIdx.x;
  if (c >= C) return;
  float s = 0.f, ss = 0.f;
  #pragma unroll
  for (int p = 0; p < 16; ++p) { s += pstats[p*2*C + c]; ss += pstats[p*2*C + C + c]; }
  float m = s * (1.f/NN);
  float v = ss * (1.f/NN) - m*m;
  stats[c] = m;
  stats[C+c] = rsqrtf(v + 1e-5f);
}

// ---------------- layer-4: bf16 MFMA GEMM with fused stats+pool epilogue ----------------

__global__ __launch_bounds__(256) void k_gemm_l4_mfma(
    const unsigned short* __restrict__ A, const unsigned short* __restrict__ Bt,
    const int* __restrict__ batch,
    float* __restrict__ stats, unsigned* __restrict__ pmax, unsigned* __restrict__ pmin) {
  __shared__ unsigned short As[128*128];
  __shared__ unsigned short Bs[128*128];
  int t = threadIdx.x;
  int row0 = blockIdx.x * 128;
  int col0 = blockIdx.y * 128;
  #pragma unroll
  for (int j = 0; j < 8; ++j) {
    int c = j*256 + t;
    int r = c >> 4, ck = c & 15;
    int rg = row0 + r;
    ulonglong2 v; v.x = 0; v.y = 0;
    if (rg < NN) v = *(const ulonglong2*)&A[rg*128 + ck*8];
    *(ulonglong2*)&As[r*128 + (ck ^ (r & 7))*8] = v;
  }
  #pragma unroll
  for (int j = 0; j < 8; ++j) {
    int c = j*256 + t;
    int r = c >> 4, ck = c & 15;
    ulonglong2 v = *(const ulonglong2*)&Bt[(col0 + r)*128 + ck*8];
    *(ulonglong2*)&Bs[r*128 + (ck ^ (r & 7))*8] = v;
  }
  __syncthreads();

  int w = t >> 6, l = t & 63;
  int wr = w >> 1, wc = w & 1;
  int lrow = l & 15, lk = l >> 4;
  f32x4 acc[4][4] = {};
  #pragma unroll
  for (int ks = 0; ks < 4; ++ks) {
    int kc = ks*4 + lk;
    bf16x8 a[4], b[4];
    #pragma unroll
    for (int m = 0; m < 4; ++m) {
      int r = wr*64 + m*16 + lrow;
      a[m] = *(const bf16x8*)&As[r*128 + (kc ^ (r & 7))*8];
    }
    #pragma unroll
    for (int n = 0; n < 4; ++n) {
      int r = wc*64 + n*16 + lrow;
      b[n] = *(const bf16x8*)&Bs[r*128 + (kc ^ (r & 7))*8];
    }
    #pragma unroll
    for (int m = 0; m < 4; ++m)
      #pragma unroll
      for (int n = 0; n < 4; ++n)
        acc[m][n] = __builtin_amdgcn_mfma_f32_16x16x32_bf16(a[m], b[n], acc[m][n], 0, 0, 0);
  }

  // ---- epilogue (no bias: b4 cancels in BN; pool argmax is shift-invariant) ----
  int rbase = row0 + wr*64;
  float s[4] = {}, ss[4] = {};
  float mx[4], mn[4];
  #pragma unroll
  for (int n = 0; n < 4; ++n) { mx[n] = -3.4e38f; mn[n] = 3.4e38f; }
  #pragma unroll
  for (int m = 0; m < 4; ++m)
    #pragma unroll
    for (int r = 0; r < 4; ++r) {
      int row_g = rbase + m*16 + lk*4 + r;
      if (row_g < NN) {
        #pragma unroll
        for (int n = 0; n < 4; ++n) {
          float v = acc[m][n][r];
          s[n] += v; ss[n] += v*v;
          mx[n] = fmaxf(mx[n], v); mn[n] = fminf(mn[n], v);
        }
      }
    }
  #pragma unroll
  for (int n = 0; n < 4; ++n) {
    s[n]  += __shfl_xor(s[n], 16);  s[n]  += __shfl_xor(s[n], 32);
    ss[n] += __shfl_xor(ss[n], 16); ss[n] += __shfl_xor(ss[n], 32);
  }
  if (l < 16) {
    #pragma unroll
    for (int n = 0; n < 4; ++n) {
      int cg = col0 + wc*64 + n*16 + l;
      atomicAdd(&stats[cg], s[n]);
      atomicAdd(&stats[1024 + cg], ss[n]);
    }
  }
  if (rbase < NN) {
    int rlast = min(rbase + 63, NN - 1);
    int glo = batch[rbase], ghi = batch[rlast];
    if (glo == ghi) {
      #pragma unroll
      for (int n = 0; n < 4; ++n) {
        mx[n] = fmaxf(mx[n], __shfl_xor(mx[n], 16)); mx[n] = fmaxf(mx[n], __shfl_xor(mx[n], 32));
        mn[n] = fminf(mn[n], __shfl_xor(mn[n], 16)); mn[n] = fminf(mn[n], __shfl_xor(mn[n], 32));
      }
      if (l < 16) {
        #pragma unroll
        for (int n = 0; n < 4; ++n) {
          int cg = col0 + wc*64 + n*16 + l;
          atomicMax(&pmax[glo*1024 + cg], fkey(mx[n]));
          atomicMin(&pmin[glo*1024 + cg], fkey(mn[n]));
        }
      }
    } else {
      int gb[4][4];
      #pragma unroll
      for (int m = 0; m < 4; ++m)
        #pragma unroll
        for (int r = 0; r < 4; ++r) {
          int row_g = rbase + m*16 + lk*4 + r;
          gb[m][r] = (row_g < NN) ? batch[row_g] : -1;
        }
      for (int g = glo; g <= ghi; ++g) {
        float gmx[4], gmn[4];
        #pragma unroll
        for (int n = 0; n < 4; ++n) { gmx[n] = -3.4e38f; gmn[n] = 3.4e38f; }
        #pragma unroll
        for (int m = 0; m < 4; ++m)
          #pragma unroll
          for (int r = 0; r < 4; ++r) {
            bool in_g = (gb[m][r] == g);
            #pragma unroll
            for (int n = 0; n < 4; ++n) {
              float v = acc[m][n][r];
              gmx[n] = in_g ? fmaxf(gmx[n], v) : gmx[n];
              gmn[n] = in_g ? fminf(gmn[n], v) : gmn[n];
            }
          }
        #pragma unroll
        for (int n = 0; n < 4; ++n) {
          gmx[n] = fmaxf(gmx[n], __shfl_xor(gmx[n], 16)); gmx[n] = fmaxf(gmx[n], __shfl_xor(gmx[n], 32));
          gmn[n] = fminf(gmn[n], __shfl_xor(gmn[n], 16)); gmn[n] = fminf(gmn[n], __shfl_xor(gmn[n], 32));
        }
        if (l < 16) {
          #pragma unroll
          for (int n = 0; n < 4; ++n) {
            int cg = col0 + wc*64 + n*16 + l;
            if (gmx[n] > -3.0e38f) atomicMax(&pmax[g*1024 + cg], fkey(gmx[n]));
            if (gmn[n] <  3.0e38f) atomicMin(&pmin[g*1024 + cg], fkey(gmn[n]));
          }
        }
      }
    }
  }
}

__global__ void k_finalize(float* stats, int C, float invN) {
  int c = blockIdx.x*blockDim.x + threadIdx.x;
  if (c < C) {
    float m = stats[c] * invN;
    float v = stats[C+c]*invN - m*m;
    stats[c] = m;
    stats[C+c] = rsqrtf(v + 1e-5f);
  }
}

// apply BN+relu to pooled raw max/min [64,1024]
__global__ void k_bnpool(const unsigned* __restrict__ pmax, const unsigned* __restrict__ pmin,
                         const float* __restrict__ stats, const float* __restrict__ g,
                         const float* __restrict__ be, float* __restrict__ p) {
  int i = blockIdx.x*256 + threadIdx.x;
  if (i >= 64*1024) return;
  int c = i & 1023;
  float mean = stats[c], rstd = stats[1024+c];
  float sc = g[c]*rstd, sh = be[c] - mean*sc;
  float v = (sc >= 0.f) ? fdec(pmax[i]) : fdec(pmin[i]);
  p[i] = fmaxf(v*sc + sh, 0.f);
}

// ---------------- FC head: K-split LDS-tiled GEMM + atomics ----------------

template<int K, int OUT, int KT>
__global__ __launch_bounds__(256) void k_fc_tile(
    const float* __restrict__ A, const float* __restrict__ W,
    float* __restrict__ out) {
  __shared__ float As[64][KT];
  __shared__ float Ws[KT][64];
  int t = threadIdx.y*64 + threadIdx.x;
  int j0 = blockIdx.x*64;
  int k0 = blockIdx.y*KT;
  #pragma unroll 4
  for (int i = t; i < 64*KT/4; i += 256) {
    int r  = i / (KT/4);
    int c4 = i % (KT/4);
    float4 v = *(const float4*)&A[r*K + k0 + c4*4];
    *(float4*)&As[r][c4*4] = v;
  }
  #pragma unroll 4
  for (int i = t; i < KT*16; i += 256) {
    int k  = i / 16;
    int c4 = i % 16;
    float4 v = *(const float4*)&W[(k0+k)*OUT + j0 + c4*4];
    *(float4*)&Ws[k][c4*4] = v;
  }
  __syncthreads();
  int j  = threadIdx.x;
  int r0 = threadIdx.y*16;
  float acc[16] = {};
  for (int kk = 0; kk < KT; ++kk) {
    float w = Ws[kk][j];
    #pragma unroll
    for (int i = 0; i < 16; ++i) acc[i] += As[r0+i][kk] * w;
  }
  #pragma unroll
  for (int i = 0; i < 16; ++i) atomicAdd(&out[(r0+i)*OUT + j0 + j], acc[i]);
}

__global__ __launch_bounds__(512) void k_bn_rows(
    float* __restrict__ h, const float* __restrict__ g,
    const float* __restrict__ be, int C) {
  int c = blockIdx.x*64 + threadIdx.x;
  int y = threadIdx.y;
  float v[8];
  float s = 0.f, ss = 0.f;
  #pragma unroll
  for (int i = 0; i < 8; ++i) {
    v[i] = h[(y*8+i)*C + c];
    s += v[i]; ss += v[i]*v[i];
  }
  __shared__ float rs[8][64], rss[8][64], bc[2][64];
  rs[y][threadIdx.x] = s; rss[y][threadIdx.x] = ss;
  __syncthreads();
  if (y == 0) {
    s = 0.f; ss = 0.f;
    #pragma unroll
    for (int i = 0; i < 8; ++i) { s += rs[i][threadIdx.x]; ss += rss[i][threadIdx.x]; }
    float m = s*(1.f/64.f);
    float var = ss*(1.f/64.f) - m*m;
    float rstd = rsqrtf(var + 1e-5f);
    float sc = g[c]*rstd;
    bc[0][threadIdx.x] = sc;
    bc[1][threadIdx.x] = be[c] - m*sc;
  }
  __syncthreads();
  float sc = bc[0][threadIdx.x], sh = bc[1][threadIdx.x];
  #pragma unroll
  for (int i = 0; i < 8; ++i)
    h[(y*8+i)*C + c] = fmaxf(v[i]*sc + sh, 0.f);
}

// add b7 then L2-normalize rows of [64,64]
__global__ void k_l2norm(const float* __restrict__ in, const float* __restrict__ b,
                         float* __restrict__ out) {
  int r = blockIdx.x, j = threadIdx.x;
  float v = in[r*64 + j] + b[j];
  float ss = v*v;
  #pragma unroll
  for (int off = 1; off < 64; off <<= 1) ss += __shfl_xor(ss, off);
  float inv = 1.f / fmaxf(sqrtf(ss), 1e-12f);
  out[r*64 + j] = v * inv;
}

// ---------------- launch ----------------

extern "C" void kernel_launch(void* const* d_in, const int* in_sizes, int n_in,
                              void* d_out, int out_size, void* d_ws, size_t ws_size,
                              hipStream_t stream) {
  const float* x    = (const float*)d_in[0];
  const int*   ei   = (const int*)d_in[1];
  const int*   batch= (const int*)d_in[2];
  const float* W1=(const float*)d_in[3],  *g1=(const float*)d_in[5],  *be1=(const float*)d_in[6];
  const float* W2=(const float*)d_in[7],  *g2=(const float*)d_in[9],  *be2=(const float*)d_in[10];
  const float* W3=(const float*)d_in[11], *g3=(const float*)d_in[13], *be3=(const float*)d_in[14];
  const float* W4=(const float*)d_in[15], *g4=(const float*)d_in[17], *be4=(const float*)d_in[18];
  const float* W5=(const float*)d_in[19], *g5=(const float*)d_in[21], *be5=(const float*)d_in[22];
  const float* W6=(const float*)d_in[23], *g6=(const float*)d_in[25], *be6=(const float*)d_in[26];
  const float* W7=(const float*)d_in[27], *b7=(const float*)d_in[28];
  const int* esrc = ei;
  const int* edst = ei + EE;

  char* w = (char*)d_ws;
  auto alloc = [&](size_t bytes) -> void* {
    void* p = (void*)w;
    w += (bytes + 255) & ~(size_t)255;
    return p;
  };
  int*   deg     = (int*)  alloc(NN*4);
  int*   offsets = (int*)  alloc((NN+1)*4);
  int*   cursor  = (int*)  alloc(NN*4);
  float* dinv    = (float*)alloc(NN*4);
  int*   csr_src = (int*)  alloc((EE+NN)*4);
  float* csr_w   = (float*)alloc((EE+NN)*4);
  float* stats1  = (float*)alloc(2*32*4);
  float* stats2  = (float*)alloc(2*64*4);
  float* stats3  = (float*)alloc(2*128*4);
  float* stats4  = (float*)alloc(2*1024*4);
  float* pstats  = (float*)alloc(16*2*128*4);
  float* agg     = (float*)alloc((size_t)NN*128*4);
  float* hbufA   = (float*)alloc((size_t)NN*128*4);
  float* hbufB   = (float*)alloc((size_t)NN*64*4);
  float* pooled  = (float*)alloc(64*1024*4);
  float* fc1     = (float*)alloc(64*512*4);
  float* fc2     = (float*)alloc(64*256*4);
  float* fc3raw  = (float*)alloc(64*64*4);
  unsigned short* agg_bf = (unsigned short*)alloc((size_t)NN*128*2);
  unsigned short* wt_bf  = (unsigned short*)alloc(1024*128*2);
  unsigned* pmax = (unsigned*)alloc(64*1024*4);
  unsigned* pmin = (unsigned*)alloc(64*1024*4);

  // graph prep
  k_prep<<<CDIV(NN,256),256,0,stream>>>(deg);
  k_deg<<<CDIV(EE,256),256,0,stream>>>(edst, deg);
  k_scan<<<1,1024,0,stream>>>(deg, offsets, cursor, dinv);
  k_fill<<<CDIV(EE+NN,256),256,0,stream>>>(esrc, edst, dinv, cursor, csr_src, csr_w);

  // ---- layer 1: agg(x) -> gemm(+stats) -> finalize ----
  k_agg<6,8,32><<<CDIV(NN,32),dim3(8,32),0,stream>>>(x, offsets, csr_src, csr_w, agg);
  hipMemsetAsync(pstats, 0, 16*2*32*4, stream);
  k_gemm_small<6,32,32><<<NN/32,256,0,stream>>>(agg, W1, hbufA, pstats);
  k_finalize_ps<32><<<1,64,0,stream>>>(pstats, stats1);

  // ---- layer 2 ----
  k_agg_f4<32,32><<<CDIV(NN,32),dim3(8,32),0,stream>>>(hbufA, stats1, g1, be1, offsets, csr_src, csr_w, agg);
  hipMemsetAsync(pstats, 0, 16*2*64*4, stream);
  k_gemm_small<32,64,16><<<NN/16,256,0,stream>>>(agg, W2, hbufB, pstats);
  k_finalize_ps<64><<<1,64,0,stream>>>(pstats, stats2);

  // ---- layer 3 ----
  k_agg_f4<64,16><<<CDIV(NN,16),dim3(16,16),0,stream>>>(hbufB, stats2, g2, be2, offsets, csr_src, csr_w, agg);
  hipMemsetAsync(pstats, 0, 16*2*128*4, stream);
  k_gemm_small<64,128,16><<<NN/16,256,0,stream>>>(agg, W3, hbufA, pstats);
  k_finalize_ps<128><<<2,64,0,stream>>>(pstats, stats3);

  // ---- layer 4: bf16 gather -> MFMA + fused stats/pool ----
  k_agg_bf_f4<<<CDIV(NN,8),dim3(32,8),0,stream>>>(hbufA, stats3, g3, be3, offsets, csr_src, csr_w, agg_bf);
  k_wprep<<<CDIV(128*1024,256),256,0,stream>>>(W4, wt_bf);
  hipMemsetAsync(stats4, 0, 2*1024*4, stream);
  hipMemsetAsync(pmax, 0x00, 64*1024*4, stream);
  hipMemsetAsync(pmin, 0xFF, 64*1024*4, stream);
  k_gemm_l4_mfma<<<dim3(CDIV(NN,128),8),256,0,stream>>>(agg_bf, wt_bf, batch, stats4, pmax, pmin);
  k_finalize<<<4,256,0,stream>>>(stats4, 1024, 1.f/NN);
  k_bnpool<<<CDIV(64*1024,256),256,0,stream>>>(pmax, pmin, stats4, g4, be4, pooled);

  // ---- FC head (b5,b6 cancel in BN; b7 added in l2norm) ----
  hipMemsetAsync(fc1, 0, 64*512*4, stream);
  k_fc_tile<1024,512,128><<<dim3(8,8),dim3(64,4),0,stream>>>(pooled, W5, fc1);
  k_bn_rows<<<8,dim3(64,8),0,stream>>>(fc1, g5, be5, 512);

  hipMemsetAsync(fc2, 0, 64*256*4, stream);
  k_fc_tile<512,256,128><<<dim3(4,4),dim3(64,4),0,stream>>>(fc1, W6, fc2);
  k_bn_rows<<<4,dim3(64,8),0,stream>>>(fc2, g6, be6, 256);

  hipMemsetAsync(fc3raw, 0, 64*64*4, stream);
  k_fc_tile<256,64,64><<<dim3(1,4),dim3(64,4),0,stream>>>(fc2, W7, fc3raw);
  k_l2norm<<<64,64,0,stream>>>(fc3raw, b7, (float*)d_out);
}

// Round 9
// 346.593 us; speedup vs baseline: 3.4779x; 1.1360x over previous
//
#include <hip/hip_runtime.h>
#include <math.h>

#define NN 20000
#define EE 256000
#define GG 64
#define CDIV(a,b) (((a)+(b)-1)/(b))

typedef __attribute__((ext_vector_type(8))) short bf16x8;
typedef __attribute__((ext_vector_type(4))) float f32x4;

__device__ __forceinline__ unsigned fkey(float f) {
  unsigned u = __float_as_uint(f);
  return (u & 0x80000000u) ? ~u : (u | 0x80000000u);
}
__device__ __forceinline__ float fdec(unsigned k) {
  unsigned u = (k & 0x80000000u) ? (k ^ 0x80000000u) : ~k;
  return __uint_as_float(u);
}
__device__ __forceinline__ unsigned short rne_bf16(float f) {
  unsigned u = __float_as_uint(f);
  unsigned r = (u + 0x7fffu + ((u >> 16) & 1u)) >> 16;
  return (unsigned short)r;
}

// ---------------- graph preprocessing ----------------

__global__ void k_prep(int* deg) {
  int i = blockIdx.x*blockDim.x + threadIdx.x;
  if (i < NN) deg[i] = 1;   // self-loop
}

__global__ void k_deg(const int* __restrict__ dst, int* deg) {
  int i = blockIdx.x*blockDim.x + threadIdx.x;
  if (i < EE) atomicAdd(&deg[dst[i]], 1);
}

// multi-block scan, stage 1: per-block (1024-elem chunk) sums
__global__ __launch_bounds__(256) void k_scan_bsum(const int* __restrict__ deg,
                                                   int* __restrict__ bsum) {
  __shared__ int red[256];
  int b = blockIdx.x, t = threadIdx.x;
  int idx = b*1024 + t*4;
  int4 v = make_int4(0,0,0,0);
  if (idx < NN) v = *(const int4*)&deg[idx];
  red[t] = v.x + v.y + v.z + v.w;
  __syncthreads();
  for (int off = 128; off > 0; off >>= 1) {
    if (t < off) red[t] += red[t+off];
    __syncthreads();
  }
  if (t == 0) bsum[b] = red[0];
}

// stage 2: apply — block base from bsum, LDS scan of 256 thread-sums (4 elems each)
__global__ __launch_bounds__(256) void k_scan_apply(
    const int* __restrict__ deg, const int* __restrict__ bsum,
    int* __restrict__ offsets, int* __restrict__ cursor, float* __restrict__ dinv) {
  __shared__ int base_s;
  __shared__ int tsum[256];
  int b = blockIdx.x, t = threadIdx.x;
  if (t == 0) {
    int s = 0;
    for (int i = 0; i < b; ++i) s += bsum[i];
    base_s = s;
  }
  int idx = b*1024 + t*4;
  int4 v = make_int4(0,0,0,0);
  if (idx < NN) v = *(const int4*)&deg[idx];
  tsum[t] = v.x + v.y + v.z + v.w;
  __syncthreads();
  for (int off = 1; off < 256; off <<= 1) {
    int u = (t >= off) ? tsum[t-off] : 0;
    __syncthreads();
    tsum[t] += u;
    __syncthreads();
  }
  int excl = (t == 0) ? 0 : tsum[t-1];
  if (idx < NN) {
    int base = base_s + excl;
    int o0 = base;
    int o1 = o0 + v.x;
    int o2 = o1 + v.y;
    int o3 = o2 + v.z;
    *(int4*)&offsets[idx] = make_int4(o0,o1,o2,o3);
    *(int4*)&cursor[idx]  = make_int4(o0,o1,o2,o3);
    float4 dv;
    dv.x = rsqrtf((float)v.x); dv.y = rsqrtf((float)v.y);
    dv.z = rsqrtf((float)v.z); dv.w = rsqrtf((float)v.w);
    *(float4*)&dinv[idx] = dv;
    if (idx + 4 == NN) offsets[NN] = o3 + v.w;
  }
}

__global__ void k_fill(const int* __restrict__ srcv, const int* __restrict__ dstv,
                       const float* __restrict__ dinv, int* cursor,
                       int* __restrict__ csr_src, float* __restrict__ csr_w) {
  int i = blockIdx.x*blockDim.x + threadIdx.x;
  if (i < EE) {
    int s = srcv[i], d = dstv[i];
    int pos = atomicAdd(&cursor[d], 1);
    csr_src[pos] = s;
    csr_w[pos] = dinv[s] * dinv[d];
  } else if (i < EE + NN) {
    int n = i - EE;
    int pos = atomicAdd(&cursor[n], 1);
    csr_src[pos] = n;
    float di = dinv[n];
    csr_w[pos] = di * di;
  }
}

// ---------------- aggregation ----------------

// layer-1: raw x input [N,6]
template<int C, int TX, int TY>
__global__ void k_agg(const float* __restrict__ in, const int* __restrict__ offsets,
                      const int* __restrict__ csr_src, const float* __restrict__ csr_w,
                      float* __restrict__ out) {
  int node = blockIdx.x * TY + threadIdx.y;
  if (node >= NN) return;
  int x = threadIdx.x;
  int k0 = offsets[node], k1 = offsets[node+1];
  if (x < C) {
    float acc = 0.f;
    for (int k = k0; k < k1; ++k) {
      int s = csr_src[k];
      float w = csr_w[k];
      acc += w * in[s*C + x];
    }
    out[node*C + x] = acc;
  }
}

// layers 2-3: gather with BN+ReLU fused on the fly, float4 lanes
template<int C, int TY>
__global__ void k_agg_f4(const float* __restrict__ in, const float* __restrict__ st,
                         const float* __restrict__ g, const float* __restrict__ be,
                         const int* __restrict__ offsets, const int* __restrict__ csr_src,
                         const float* __restrict__ csr_w, float* __restrict__ out) {
  int node = blockIdx.x*TY + threadIdx.y;
  if (node >= NN) return;
  int c0 = threadIdx.x*4;
  float4 mean = *(const float4*)&st[c0];
  float4 rstd = *(const float4*)&st[C+c0];
  float4 gv = *(const float4*)&g[c0];
  float4 bv = *(const float4*)&be[c0];
  float sx = gv.x*rstd.x, hx = bv.x - mean.x*sx;
  float sy = gv.y*rstd.y, hy = bv.y - mean.y*sy;
  float sz = gv.z*rstd.z, hz = bv.z - mean.z*sz;
  float sw = gv.w*rstd.w, hw = bv.w - mean.w*sw;
  int k0 = offsets[node], k1 = offsets[node+1];
  float a0=0.f,a1=0.f,a2=0.f,a3=0.f;
  for (int k = k0; k < k1; ++k) {
    int s = csr_src[k]; float w = csr_w[k];
    float4 v = *(const float4*)&in[s*C + c0];
    a0 += w*fmaxf(v.x*sx+hx, 0.f);
    a1 += w*fmaxf(v.y*sy+hy, 0.f);
    a2 += w*fmaxf(v.z*sz+hz, 0.f);
    a3 += w*fmaxf(v.w*sw+hw, 0.f);
  }
  *(float4*)&out[node*C+c0] = make_float4(a0,a1,a2,a3);
}

// layer-4: gather [N,128] with BN+ReLU fused, emits bf16
__global__ void k_agg_bf_f4(const float* __restrict__ in, const float* __restrict__ st,
                            const float* __restrict__ g, const float* __restrict__ be,
                            const int* __restrict__ offsets, const int* __restrict__ csr_src,
                            const float* __restrict__ csr_w, unsigned short* __restrict__ out) {
  int node = blockIdx.x*8 + threadIdx.y;   // block (32,8)
  if (node >= NN) return;
  int c0 = threadIdx.x*4;
  float4 mean = *(const float4*)&st[c0];
  float4 rstd = *(const float4*)&st[128+c0];
  float4 gv = *(const float4*)&g[c0];
  float4 bv = *(const float4*)&be[c0];
  float sx = gv.x*rstd.x, hx = bv.x - mean.x*sx;
  float sy = gv.y*rstd.y, hy = bv.y - mean.y*sy;
  float sz = gv.z*rstd.z, hz = bv.z - mean.z*sz;
  float sw = gv.w*rstd.w, hw = bv.w - mean.w*sw;
  int k0 = offsets[node], k1 = offsets[node+1];
  float a0=0.f,a1=0.f,a2=0.f,a3=0.f;
  for (int k = k0; k < k1; ++k) {
    int s = csr_src[k]; float w = csr_w[k];
    float4 v = *(const float4*)&in[s*128 + c0];
    a0 += w*fmaxf(v.x*sx+hx, 0.f);
    a1 += w*fmaxf(v.y*sy+hy, 0.f);
    a2 += w*fmaxf(v.z*sz+hz, 0.f);
    a3 += w*fmaxf(v.w*sw+hw, 0.f);
  }
  ushort4 o;
  o.x = rne_bf16(a0); o.y = rne_bf16(a1); o.z = rne_bf16(a2); o.w = rne_bf16(a3);
  *(ushort4*)&out[node*128 + c0] = o;
}

// W4 [128,1024] fp32 -> Wt [1024,128] bf16
__global__ void k_wprep(const float* __restrict__ W, unsigned short* __restrict__ out) {
  int i = blockIdx.x*256 + threadIdx.x;
  if (i >= 128*1024) return;
  int k = i >> 10, c = i & 1023;
  out[c*128 + k] = rne_bf16(W[i]);
}

// ---------------- small GEMM (layers 1-3), no bias, fused stats ----------------

template<int K, int OUT, int ROWS>
__global__ __launch_bounds__(256) void k_gemm_small(
    const float* __restrict__ A, const float* __restrict__ W,
    float* __restrict__ out, float* __restrict__ pstats) {
  constexpr int RG  = 256 / OUT;
  constexpr int RPT = ROWS / RG;
  __shared__ float Ws[K*OUT];
  __shared__ float As[ROWS*K];
  __shared__ float reds[2][RG][OUT];
  int t = threadIdx.x;
  for (int i = t; i < K*OUT; i += 256) Ws[i] = W[i];
  int row0 = blockIdx.x * ROWS;
  for (int i = t; i < ROWS*K; i += 256) As[i] = A[row0*K + i];
  __syncthreads();
  int j  = t % OUT;
  int rg = t / OUT;
  float acc[RPT] = {};
  for (int k = 0; k < K; ++k) {
    float w = Ws[k*OUT + j];
    #pragma unroll
    for (int i = 0; i < RPT; ++i)
      acc[i] += As[(rg*RPT + i)*K + k] * w;
  }
  float s = 0.f, ss = 0.f;
  #pragma unroll
  for (int i = 0; i < RPT; ++i) {
    out[(row0 + rg*RPT + i)*OUT + j] = acc[i];
    s += acc[i]; ss += acc[i]*acc[i];
  }
  reds[0][rg][j] = s; reds[1][rg][j] = ss;
  __syncthreads();
  if (rg == 0) {
    float S = 0.f, SS = 0.f;
    #pragma unroll
    for (int r = 0; r < RG; ++r) { S += reds[0][r][j]; SS += reds[1][r][j]; }
    int p = blockIdx.x & 15;
    atomicAdd(&pstats[p*2*OUT + j], S);
    atomicAdd(&pstats[p*2*OUT + OUT + j], SS);
  }
}

template<int C>
__global__ void k_finalize_ps(const float* __restrict__ pstats, float* __restrict__ stats) {
  int c = blockIdx.x*64 + threadIdx.x;
  if (c >= C) return;
  float s = 0.f, ss = 0.f;
  #pragma unroll
  for (int p = 0; p < 16; ++p) { s += pstats[p*2*C + c]; ss += pstats[p*2*C + C + c]; }
  float m = s * (1.f/NN);
  float v = ss * (1.f/NN) - m*m;
  stats[c] = m;
  stats[C+c] = rsqrtf(v + 1e-5f);
}

// ---------------- layer-4: bf16 MFMA GEMM with fused stats+pool epilogue ----------------

__global__ __launch_bounds__(256) void k_gemm_l4_mfma(
    const unsigned short* __restrict__ A, const unsigned short* __restrict__ Bt,
    const int* __restrict__ batch,
    float* __restrict__ stats, unsigned* __restrict__ pmax, unsigned* __restrict__ pmin) {
  __shared__ unsigned short As[128*128];
  __shared__ unsigned short Bs[128*128];
  int t = threadIdx.x;
  int row0 = blockIdx.x * 128;
  int col0 = blockIdx.y * 128;
  #pragma unroll
  for (int j = 0; j < 8; ++j) {
    int c = j*256 + t;
    int r = c >> 4, ck = c & 15;
    int rg = row0 + r;
    ulonglong2 v; v.x = 0; v.y = 0;
    if (rg < NN) v = *(const ulonglong2*)&A[rg*128 + ck*8];
    *(ulonglong2*)&As[r*128 + (ck ^ (r & 7))*8] = v;
  }
  #pragma unroll
  for (int j = 0; j < 8; ++j) {
    int c = j*256 + t;
    int r = c >> 4, ck = c & 15;
    ulonglong2 v = *(const ulonglong2*)&Bt[(col0 + r)*128 + ck*8];
    *(ulonglong2*)&Bs[r*128 + (ck ^ (r & 7))*8] = v;
  }
  __syncthreads();

  int w = t >> 6, l = t & 63;
  int wr = w >> 1, wc = w & 1;
  int lrow = l & 15, lk = l >> 4;
  f32x4 acc[4][4] = {};
  #pragma unroll
  for (int ks = 0; ks < 4; ++ks) {
    int kc = ks*4 + lk;
    bf16x8 a[4], b[4];
    #pragma unroll
    for (int m = 0; m < 4; ++m) {
      int r = wr*64 + m*16 + lrow;
      a[m] = *(const bf16x8*)&As[r*128 + (kc ^ (r & 7))*8];
    }
    #pragma unroll
    for (int n = 0; n < 4; ++n) {
      int r = wc*64 + n*16 + lrow;
      b[n] = *(const bf16x8*)&Bs[r*128 + (kc ^ (r & 7))*8];
    }
    #pragma unroll
    for (int m = 0; m < 4; ++m)
      #pragma unroll
      for (int n = 0; n < 4; ++n)
        acc[m][n] = __builtin_amdgcn_mfma_f32_16x16x32_bf16(a[m], b[n], acc[m][n], 0, 0, 0);
  }

  // ---- epilogue (no bias: b4 cancels in BN; pool argmax is shift-invariant) ----
  int rbase = row0 + wr*64;
  float s[4] = {}, ss[4] = {};
  float mx[4], mn[4];
  #pragma unroll
  for (int n = 0; n < 4; ++n) { mx[n] = -3.4e38f; mn[n] = 3.4e38f; }
  #pragma unroll
  for (int m = 0; m < 4; ++m)
    #pragma unroll
    for (int r = 0; r < 4; ++r) {
      int row_g = rbase + m*16 + lk*4 + r;
      if (row_g < NN) {
        #pragma unroll
        for (int n = 0; n < 4; ++n) {
          float v = acc[m][n][r];
          s[n] += v; ss[n] += v*v;
          mx[n] = fmaxf(mx[n], v); mn[n] = fminf(mn[n], v);
        }
      }
    }
  #pragma unroll
  for (int n = 0; n < 4; ++n) {
    s[n]  += __shfl_xor(s[n], 16);  s[n]  += __shfl_xor(s[n], 32);
    ss[n] += __shfl_xor(ss[n], 16); ss[n] += __shfl_xor(ss[n], 32);
  }
  if (l < 16) {
    #pragma unroll
    for (int n = 0; n < 4; ++n) {
      int cg = col0 + wc*64 + n*16 + l;
      atomicAdd(&stats[cg], s[n]);
      atomicAdd(&stats[1024 + cg], ss[n]);
    }
  }
  if (rbase < NN) {
    int rlast = min(rbase + 63, NN - 1);
    int glo = batch[rbase], ghi = batch[rlast];
    if (glo == ghi) {
      #pragma unroll
      for (int n = 0; n < 4; ++n) {
        mx[n] = fmaxf(mx[n], __shfl_xor(mx[n], 16)); mx[n] = fmaxf(mx[n], __shfl_xor(mx[n], 32));
        mn[n] = fminf(mn[n], __shfl_xor(mn[n], 16)); mn[n] = fminf(mn[n], __shfl_xor(mn[n], 32));
      }
      if (l < 16) {
        #pragma unroll
        for (int n = 0; n < 4; ++n) {
          int cg = col0 + wc*64 + n*16 + l;
          atomicMax(&pmax[glo*1024 + cg], fkey(mx[n]));
          atomicMin(&pmin[glo*1024 + cg], fkey(mn[n]));
        }
      }
    } else {
      int gb[4][4];
      #pragma unroll
      for (int m = 0; m < 4; ++m)
        #pragma unroll
        for (int r = 0; r < 4; ++r) {
          int row_g = rbase + m*16 + lk*4 + r;
          gb[m][r] = (row_g < NN) ? batch[row_g] : -1;
        }
      for (int g = glo; g <= ghi; ++g) {
        float gmx[4], gmn[4];
        #pragma unroll
        for (int n = 0; n < 4; ++n) { gmx[n] = -3.4e38f; gmn[n] = 3.4e38f; }
        #pragma unroll
        for (int m = 0; m < 4; ++m)
          #pragma unroll
          for (int r = 0; r < 4; ++r) {
            bool in_g = (gb[m][r] == g);
            #pragma unroll
            for (int n = 0; n < 4; ++n) {
              float v = acc[m][n][r];
              gmx[n] = in_g ? fmaxf(gmx[n], v) : gmx[n];
              gmn[n] = in_g ? fminf(gmn[n], v) : gmn[n];
            }
          }
        #pragma unroll
        for (int n = 0; n < 4; ++n) {
          gmx[n] = fmaxf(gmx[n], __shfl_xor(gmx[n], 16)); gmx[n] = fmaxf(gmx[n], __shfl_xor(gmx[n], 32));
          gmn[n] = fminf(gmn[n], __shfl_xor(gmn[n], 16)); gmn[n] = fminf(gmn[n], __shfl_xor(gmn[n], 32));
        }
        if (l < 16) {
          #pragma unroll
          for (int n = 0; n < 4; ++n) {
            int cg = col0 + wc*64 + n*16 + l;
            if (gmx[n] > -3.0e38f) atomicMax(&pmax[g*1024 + cg], fkey(gmx[n]));
            if (gmn[n] <  3.0e38f) atomicMin(&pmin[g*1024 + cg], fkey(gmn[n]));
          }
        }
      }
    }
  }
}

__global__ void k_finalize(float* stats, int C, float invN) {
  int c = blockIdx.x*blockDim.x + threadIdx.x;
  if (c < C) {
    float m = stats[c] * invN;
    float v = stats[C+c]*invN - m*m;
    stats[c] = m;
    stats[C+c] = rsqrtf(v + 1e-5f);
  }
}

// apply BN+relu to pooled raw max/min [64,1024]
__global__ void k_bnpool(const unsigned* __restrict__ pmax, const unsigned* __restrict__ pmin,
                         const float* __restrict__ stats, const float* __restrict__ g,
                         const float* __restrict__ be, float* __restrict__ p) {
  int i = blockIdx.x*256 + threadIdx.x;
  if (i >= 64*1024) return;
  int c = i & 1023;
  float mean = stats[c], rstd = stats[1024+c];
  float sc = g[c]*rstd, sh = be[c] - mean*sc;
  float v = (sc >= 0.f) ? fdec(pmax[i]) : fdec(pmin[i]);
  p[i] = fmaxf(v*sc + sh, 0.f);
}

// ---------------- FC head: K-split LDS-tiled GEMM + atomics ----------------

template<int K, int OUT, int KT>
__global__ __launch_bounds__(256) void k_fc_tile(
    const float* __restrict__ A, const float* __restrict__ W,
    float* __restrict__ out) {
  __shared__ float As[64][KT];
  __shared__ float Ws[KT][64];
  int t = threadIdx.y*64 + threadIdx.x;
  int j0 = blockIdx.x*64;
  int k0 = blockIdx.y*KT;
  #pragma unroll 4
  for (int i = t; i < 64*KT/4; i += 256) {
    int r  = i / (KT/4);
    int c4 = i % (KT/4);
    float4 v = *(const float4*)&A[r*K + k0 + c4*4];
    *(float4*)&As[r][c4*4] = v;
  }
  #pragma unroll 4
  for (int i = t; i < KT*16; i += 256) {
    int k  = i / 16;
    int c4 = i % 16;
    float4 v = *(const float4*)&W[(k0+k)*OUT + j0 + c4*4];
    *(float4*)&Ws[k][c4*4] = v;
  }
  __syncthreads();
  int j  = threadIdx.x;
  int r0 = threadIdx.y*16;
  float acc[16] = {};
  for (int kk = 0; kk < KT; ++kk) {
    float w = Ws[kk][j];
    #pragma unroll
    for (int i = 0; i < 16; ++i) acc[i] += As[r0+i][kk] * w;
  }
  #pragma unroll
  for (int i = 0; i < 16; ++i) atomicAdd(&out[(r0+i)*OUT + j0 + j], acc[i]);
}

__global__ __launch_bounds__(512) void k_bn_rows(
    float* __restrict__ h, const float* __restrict__ g,
    const float* __restrict__ be, int C) {
  int c = blockIdx.x*64 + threadIdx.x;
  int y = threadIdx.y;
  float v[8];
  float s = 0.f, ss = 0.f;
  #pragma unroll
  for (int i = 0; i < 8; ++i) {
    v[i] = h[(y*8+i)*C + c];
    s += v[i]; ss += v[i]*v[i];
  }
  __shared__ float rs[8][64], rss[8][64], bc[2][64];
  rs[y][threadIdx.x] = s; rss[y][threadIdx.x] = ss;
  __syncthreads();
  if (y == 0) {
    s = 0.f; ss = 0.f;
    #pragma unroll
    for (int i = 0; i < 8; ++i) { s += rs[i][threadIdx.x]; ss += rss[i][threadIdx.x]; }
    float m = s*(1.f/64.f);
    float var = ss*(1.f/64.f) - m*m;
    float rstd = rsqrtf(var + 1e-5f);
    float sc = g[c]*rstd;
    bc[0][threadIdx.x] = sc;
    bc[1][threadIdx.x] = be[c] - m*sc;
  }
  __syncthreads();
  float sc = bc[0][threadIdx.x], sh = bc[1][threadIdx.x];
  #pragma unroll
  for (int i = 0; i < 8; ++i)
    h[(y*8+i)*C + c] = fmaxf(v[i]*sc + sh, 0.f);
}

// add b7 then L2-normalize rows of [64,64]
__global__ void k_l2norm(const float* __restrict__ in, const float* __restrict__ b,
                         float* __restrict__ out) {
  int r = blockIdx.x, j = threadIdx.x;
  float v = in[r*64 + j] + b[j];
  float ss = v*v;
  #pragma unroll
  for (int off = 1; off < 64; off <<= 1) ss += __shfl_xor(ss, off);
  float inv = 1.f / fmaxf(sqrtf(ss), 1e-12f);
  out[r*64 + j] = v * inv;
}

// ---------------- launch ----------------

extern "C" void kernel_launch(void* const* d_in, const int* in_sizes, int n_in,
                              void* d_out, int out_size, void* d_ws, size_t ws_size,
                              hipStream_t stream) {
  const float* x    = (const float*)d_in[0];
  const int*   ei   = (const int*)d_in[1];
  const int*   batch= (const int*)d_in[2];
  const float* W1=(const float*)d_in[3],  *g1=(const float*)d_in[5],  *be1=(const float*)d_in[6];
  const float* W2=(const float*)d_in[7],  *g2=(const float*)d_in[9],  *be2=(const float*)d_in[10];
  const float* W3=(const float*)d_in[11], *g3=(const float*)d_in[13], *be3=(const float*)d_in[14];
  const float* W4=(const float*)d_in[15], *g4=(const float*)d_in[17], *be4=(const float*)d_in[18];
  const float* W5=(const float*)d_in[19], *g5=(const float*)d_in[21], *be5=(const float*)d_in[22];
  const float* W6=(const float*)d_in[23], *g6=(const float*)d_in[25], *be6=(const float*)d_in[26];
  const float* W7=(const float*)d_in[27], *b7=(const float*)d_in[28];
  const int* esrc = ei;
  const int* edst = ei + EE;

  char* w = (char*)d_ws;
  auto alloc = [&](size_t bytes) -> void* {
    void* p = (void*)w;
    w += (bytes + 255) & ~(size_t)255;
    return p;
  };
  int*   deg     = (int*)  alloc(NN*4);
  int*   offsets = (int*)  alloc((NN+1)*4);
  int*   cursor  = (int*)  alloc(NN*4);
  int*   bsum    = (int*)  alloc(32*4);
  float* dinv    = (float*)alloc(NN*4);
  int*   csr_src = (int*)  alloc((EE+NN)*4);
  float* csr_w   = (float*)alloc((EE+NN)*4);
  float* stats1  = (float*)alloc(2*32*4);
  float* stats2  = (float*)alloc(2*64*4);
  float* stats3  = (float*)alloc(2*128*4);
  float* stats4  = (float*)alloc(2*1024*4);
  float* pstats  = (float*)alloc(16*2*128*4);
  float* agg     = (float*)alloc((size_t)NN*128*4);
  float* hbufA   = (float*)alloc((size_t)NN*128*4);
  float* hbufB   = (float*)alloc((size_t)NN*64*4);
  float* pooled  = (float*)alloc(64*1024*4);
  float* fc1     = (float*)alloc(64*512*4);
  float* fc2     = (float*)alloc(64*256*4);
  float* fc3raw  = (float*)alloc(64*64*4);
  unsigned short* agg_bf = (unsigned short*)alloc((size_t)NN*128*2);
  unsigned short* wt_bf  = (unsigned short*)alloc(1024*128*2);
  unsigned* pmax = (unsigned*)alloc(64*1024*4);
  unsigned* pmin = (unsigned*)alloc(64*1024*4);

  // graph prep (multi-block scan)
  k_prep<<<CDIV(NN,256),256,0,stream>>>(deg);
  k_deg<<<CDIV(EE,256),256,0,stream>>>(edst, deg);
  k_scan_bsum<<<20,256,0,stream>>>(deg, bsum);
  k_scan_apply<<<20,256,0,stream>>>(deg, bsum, offsets, cursor, dinv);
  k_fill<<<CDIV(EE+NN,256),256,0,stream>>>(esrc, edst, dinv, cursor, csr_src, csr_w);

  // ---- layer 1: agg(x) -> gemm(+stats) -> finalize ----
  k_agg<6,8,32><<<CDIV(NN,32),dim3(8,32),0,stream>>>(x, offsets, csr_src, csr_w, agg);
  hipMemsetAsync(pstats, 0, 16*2*32*4, stream);
  k_gemm_small<6,32,32><<<NN/32,256,0,stream>>>(agg, W1, hbufA, pstats);
  k_finalize_ps<32><<<1,64,0,stream>>>(pstats, stats1);

  // ---- layer 2 ----
  k_agg_f4<32,32><<<CDIV(NN,32),dim3(8,32),0,stream>>>(hbufA, stats1, g1, be1, offsets, csr_src, csr_w, agg);
  hipMemsetAsync(pstats, 0, 16*2*64*4, stream);
  k_gemm_small<32,64,16><<<NN/16,256,0,stream>>>(agg, W2, hbufB, pstats);
  k_finalize_ps<64><<<1,64,0,stream>>>(pstats, stats2);

  // ---- layer 3 ----
  k_agg_f4<64,16><<<CDIV(NN,16),dim3(16,16),0,stream>>>(hbufB, stats2, g2, be2, offsets, csr_src, csr_w, agg);
  hipMemsetAsync(pstats, 0, 16*2*128*4, stream);
  k_gemm_small<64,128,16><<<NN/16,256,0,stream>>>(agg, W3, hbufA, pstats);
  k_finalize_ps<128><<<2,64,0,stream>>>(pstats, stats3);

  // ---- layer 4: bf16 gather -> MFMA + fused stats/pool ----
  k_agg_bf_f4<<<CDIV(NN,8),dim3(32,8),0,stream>>>(hbufA, stats3, g3, be3, offsets, csr_src, csr_w, agg_bf);
  k_wprep<<<CDIV(128*1024,256),256,0,stream>>>(W4, wt_bf);
  hipMemsetAsync(stats4, 0, 2*1024*4, stream);
  hipMemsetAsync(pmax, 0x00, 64*1024*4, stream);
  hipMemsetAsync(pmin, 0xFF, 64*1024*4, stream);
  k_gemm_l4_mfma<<<dim3(CDIV(NN,128),8),256,0,stream>>>(agg_bf, wt_bf, batch, stats4, pmax, pmin);
  k_finalize<<<4,256,0,stream>>>(stats4, 1024, 1.f/NN);
  k_bnpool<<<CDIV(64*1024,256),256,0,stream>>>(pmax, pmin, stats4, g4, be4, pooled);

  // ---- FC head (b5,b6 cancel in BN; b7 added in l2norm) ----
  hipMemsetAsync(fc1, 0, 64*512*4, stream);
  k_fc_tile<1024,512,128><<<dim3(8,8),dim3(64,4),0,stream>>>(pooled, W5, fc1);
  k_bn_rows<<<8,dim3(64,8),0,stream>>>(fc1, g5, be5, 512);

  hipMemsetAsync(fc2, 0, 64*256*4, stream);
  k_fc_tile<512,256,128><<<dim3(4,4),dim3(64,4),0,stream>>>(fc1, W6, fc2);
  k_bn_rows<<<4,dim3(64,8),0,stream>>>(fc2, g6, be6, 256);

  hipMemsetAsync(fc3raw, 0, 64*64*4, stream);
  k_fc_tile<256,64,64><<<dim3(1,4),dim3(64,4),0,stream>>>(fc2, W7, fc3raw);
  k_l2norm<<<64,64,0,stream>>>(fc3raw, b7, (float*)d_out);
}